// Round 1
// baseline (569.592 us; speedup 1.0000x reference)
//
#include <hip/hip_runtime.h>
#include <math.h>

// Problem constants (fixed by reference)
#define BB   16
#define LATD 8
#define NN   500000
#define XSZ  256
#define HALF 128
#define IMG_ELEMS (BB * XSZ * XSZ)          // 1,048,576 floats
#define FREQ_COLS 129                        // XS/2+1

// ---------------------------------------------------------------------------
// K0: per-image prep — rotation rows 0/1, shifts+half, SIREN MLP hidden h[8]
// bdata layout per b (16 floats): R00,R01,R02,R10,R11,R12, sx, sy, h0..h7
// ---------------------------------------------------------------------------
__global__ void prep_kernel(const float* __restrict__ rows,
                            const float* __restrict__ shifts,
                            const float* __restrict__ latent,
                            const float* __restrict__ W0, const float* __restrict__ b0,
                            const float* __restrict__ W1, const float* __restrict__ b1,
                            const float* __restrict__ W2, const float* __restrict__ b2,
                            const float* __restrict__ W3, const float* __restrict__ b3,
                            float* __restrict__ bdata) {
    int b = threadIdx.x;
    if (b >= BB) return;

    float rot  = rows[b * 3 + 0];
    float tilt = rows[b * 3 + 1];
    float psi  = rows[b * 3 + 2];
    float ca, sa, cb, sb, cg, sg;
    sincosf(rot, &sa, &ca);
    sincosf(tilt, &sb, &cb);
    sincosf(psi, &sg, &cg);

    float R00 =  cg * cb * ca - sg * sa;
    float R01 =  cg * cb * sa + sg * ca;
    float R02 = -cg * sb;
    float R10 = -sg * cb * ca - cg * sa;
    float R11 = -sg * cb * sa + cg * ca;
    float R12 =  sg * sb;

    float h[LATD], t[LATD];
    #pragma unroll
    for (int j = 0; j < LATD; ++j) {
        float acc = b0[j];
        #pragma unroll
        for (int l = 0; l < LATD; ++l) acc += latent[b * LATD + l] * W0[l * LATD + j];
        t[j] = acc;
    }
    #pragma unroll
    for (int j = 0; j < LATD; ++j) h[j] = sinf(30.0f * t[j]);

    const float* Ws[3] = {W1, W2, W3};
    const float* bs[3] = {b1, b2, b3};
    for (int L = 0; L < 3; ++L) {
        #pragma unroll
        for (int j = 0; j < LATD; ++j) {
            float acc = bs[L][j];
            #pragma unroll
            for (int l = 0; l < LATD; ++l) acc += h[l] * Ws[L][l * LATD + j];
            t[j] = acc;
        }
        #pragma unroll
        for (int j = 0; j < LATD; ++j) h[j] += sinf(t[j]);
    }

    float* P = bdata + b * 16;
    P[0] = R00; P[1] = R01; P[2] = R02;
    P[3] = R10; P[4] = R11; P[5] = R12;
    P[6] = shifts[b * 2 + 0] + (float)HALF;
    P[7] = shifts[b * 2 + 1] + (float)HALF;
    #pragma unroll
    for (int j = 0; j < LATD; ++j) P[8 + j] = h[j];
}

// ---------------------------------------------------------------------------
// K1: zero image buffer (float4 stores)
// ---------------------------------------------------------------------------
__global__ void zero_kernel(float4* __restrict__ p) {
    int i = blockIdx.x * blockDim.x + threadIdx.x;   // 262144 float4 = 1M floats
    p[i] = make_float4(0.f, 0.f, 0.f, 0.f);
}

// ---------------------------------------------------------------------------
// K2: scatter — for each point n, for each image b: rotate, round, clip,
// delta = h_b . Wd[:,n], atomicAdd into img.
// ---------------------------------------------------------------------------
__global__ __launch_bounds__(256) void scatter_kernel(
        const float* __restrict__ coords, const float* __restrict__ values,
        const float* __restrict__ Wd, const float* __restrict__ bd,
        const float* __restrict__ bdata, float* __restrict__ img) {
    __shared__ float P[BB * 16];
    P[threadIdx.x] = bdata[threadIdx.x];
    __syncthreads();

    int n = blockIdx.x * 256 + threadIdx.x;
    if (n >= NN) return;

    float cx = coords[n * 3 + 0];
    float cy = coords[n * 3 + 1];
    float cz = coords[n * 3 + 2];
    float base = values[n] + bd[n];

    float wd[LATD];
    #pragma unroll
    for (int l = 0; l < LATD; ++l) wd[l] = Wd[l * NN + n];

    #pragma unroll
    for (int b = 0; b < BB; ++b) {
        const float* Q = &P[b * 16];
        float x = fmaf(Q[0], cx, fmaf(Q[1], cy, fmaf(Q[2], cz, Q[6])));
        float y = fmaf(Q[3], cx, fmaf(Q[4], cy, fmaf(Q[5], cz, Q[7])));
        float px = fminf(fmaxf(rintf(x), 0.f), 255.f);
        float py = fminf(fmaxf(rintf(y), 0.f), 255.f);
        int ipx = (int)px;
        int ipy = (int)py;
        float delta = 0.f;
        #pragma unroll
        for (int l = 0; l < LATD; ++l) delta = fmaf(Q[8 + l], wd[l], delta);
        atomicAdd(img + ((b << 16) | (ipy << 8) | ipx), base + delta);
    }
}

// ---------------------------------------------------------------------------
// K3/K4: separable 7-tap Gaussian blur, zero padding ('SAME')
// ---------------------------------------------------------------------------
__device__ __constant__ float GW[4] = {0.39905027f, 0.24203623f, 0.05400558f, 0.00443305f};

__global__ void blur_h_kernel(const float* __restrict__ in, float* __restrict__ out) {
    int idx = blockIdx.x * blockDim.x + threadIdx.x;  // < IMG_ELEMS
    int y = (idx >> 8) & 255;
    float acc = GW[0] * in[idx];
    #pragma unroll
    for (int t = 1; t <= 3; ++t) {
        if (y - t >= 0)  acc += GW[t] * in[idx - t * 256];
        if (y + t < 256) acc += GW[t] * in[idx + t * 256];
    }
    out[idx] = acc;
}

__global__ void blur_w_kernel(const float* __restrict__ in, float* __restrict__ out) {
    int idx = blockIdx.x * blockDim.x + threadIdx.x;
    int x = idx & 255;
    float acc = GW[0] * in[idx];
    #pragma unroll
    for (int t = 1; t <= 3; ++t) {
        if (x - t >= 0)  acc += GW[t] * in[idx - t];
        if (x + t < 256) acc += GW[t] * in[idx + t];
    }
    out[idx] = acc;
}

// ---------------------------------------------------------------------------
// 256-point complex Stockham FFT in LDS, 64 threads, 8 radix-2 stages.
// dir = -1 forward (exp(-i)), +1 inverse (exp(+i), unnormalized).
// Result lands back in s0. Each stage ends with __syncthreads().
// ---------------------------------------------------------------------------
__device__ __forceinline__ void fft256(float2* s0, float2* s1, int tid, float dir) {
    float2* src = s0;
    float2* dst = s1;
    const float base = dir * 0.0245436926061703f;   // 2*pi/256
    #pragma unroll
    for (int t = 0; t < 8; ++t) {
        const int s = 1 << t;
        #pragma unroll
        for (int r = 0; r < 2; ++r) {
            int i = tid + (r << 6);          // 0..127
            int q = i & (s - 1);
            int p = i >> t;                  // 0..(128>>t)-1
            float2 a = src[q + s * p];
            float2 b = src[q + s * p + 128];
            float ang = base * (float)(p << t);
            float sn, cs;
            sincosf(ang, &sn, &cs);
            float2 sum = make_float2(a.x + b.x, a.y + b.y);
            float dx = a.x - b.x;
            float dy = a.y - b.y;
            float2 tw = make_float2(dx * cs - dy * sn, dx * sn + dy * cs);
            int o = q + ((p * s) << 1);
            dst[o] = sum;
            dst[o + s] = tw;
        }
        __syncthreads();
        float2* tmp = src; src = dst; dst = tmp;
    }
}

// K5: forward row rFFT (real 256 -> 129 complex), write transposed Freq[b][col][y]
__global__ __launch_bounds__(64) void fft_rows_fwd(const float* __restrict__ img,
                                                   float2* __restrict__ Freq) {
    __shared__ float2 bufA[256];
    __shared__ float2 bufB[256];
    int tid = threadIdx.x;
    int b = blockIdx.x >> 8;
    int y = blockIdx.x & 255;
    const float* row = img + ((size_t)blockIdx.x << 8);
    #pragma unroll
    for (int j = 0; j < 4; ++j) {
        int idx = tid + (j << 6);
        bufA[idx] = make_float2(row[idx], 0.f);
    }
    __syncthreads();
    fft256(bufA, bufB, tid, -1.f);
    for (int col = tid; col < FREQ_COLS; col += 64) {
        Freq[((size_t)(b * FREQ_COLS + col) << 8) + y] = bufA[col];
    }
}

// K6: column FFT + CTF multiply + inverse column FFT (all in LDS)
__global__ __launch_bounds__(64) void fft_cols_ctf(float2* __restrict__ Freq,
                                                   const float* __restrict__ ctf) {
    __shared__ float2 bufA[256];
    __shared__ float2 bufB[256];
    int tid = threadIdx.x;
    int b = blockIdx.x / FREQ_COLS;
    int col = blockIdx.x - b * FREQ_COLS;
    float2* basep = Freq + ((size_t)(b * FREQ_COLS + col) << 8);
    #pragma unroll
    for (int j = 0; j < 4; ++j) {
        int idx = tid + (j << 6);
        bufA[idx] = basep[idx];
    }
    __syncthreads();
    fft256(bufA, bufB, tid, -1.f);
    #pragma unroll
    for (int j = 0; j < 4; ++j) {
        int k = tid + (j << 6);
        float c = ctf[(size_t)((b << 8) | k) * FREQ_COLS + col];
        bufA[k].x *= c;
        bufA[k].y *= c;
    }
    __syncthreads();
    fft256(bufA, bufB, tid, +1.f);
    #pragma unroll
    for (int j = 0; j < 4; ++j) {
        int idx = tid + (j << 6);
        basep[idx] = bufA[idx];
    }
}

// K7: inverse row rFFT — Hermitian-extend 129 -> 256, inverse FFT, real part,
// scale by 1/(256*256)
__global__ __launch_bounds__(64) void fft_rows_inv(const float2* __restrict__ Freq,
                                                   float* __restrict__ out) {
    __shared__ float2 bufA[256];
    __shared__ float2 bufB[256];
    int tid = threadIdx.x;
    int b = blockIdx.x >> 8;
    int y = blockIdx.x & 255;
    for (int col = tid; col < FREQ_COLS; col += 64) {
        bufA[col] = Freq[((size_t)(b * FREQ_COLS + col) << 8) + y];
    }
    __syncthreads();
    for (int k = 129 + tid; k < 256; k += 64) {
        float2 v = bufA[256 - k];
        bufA[k] = make_float2(v.x, -v.y);
    }
    __syncthreads();
    fft256(bufA, bufB, tid, +1.f);
    float* row = out + ((size_t)blockIdx.x << 8);
    const float scale = 1.0f / 65536.0f;
    #pragma unroll
    for (int j = 0; j < 4; ++j) {
        int idx = tid + (j << 6);
        row[idx] = bufA[idx].x * scale;
    }
}

// ---------------------------------------------------------------------------
extern "C" void kernel_launch(void* const* d_in, const int* in_sizes, int n_in,
                              void* d_out, int out_size, void* d_ws, size_t ws_size,
                              hipStream_t stream) {
    const float* rows   = (const float*)d_in[0];
    const float* shifts = (const float*)d_in[1];
    const float* latent = (const float*)d_in[2];
    const float* coords = (const float*)d_in[3];
    const float* values = (const float*)d_in[4];
    const float* W0     = (const float*)d_in[5];
    const float* b0     = (const float*)d_in[6];
    const float* W1     = (const float*)d_in[7];
    const float* b1     = (const float*)d_in[8];
    const float* W2     = (const float*)d_in[9];
    const float* b2     = (const float*)d_in[10];
    const float* W3     = (const float*)d_in[11];
    const float* b3     = (const float*)d_in[12];
    const float* Wd     = (const float*)d_in[13];
    const float* bd     = (const float*)d_in[14];
    const float* ctf    = (const float*)d_in[15];
    float* out = (float*)d_out;

    char* w = (char*)d_ws;
    float*  bdata = (float*)(w);                         // 256 floats
    float*  img   = (float*)(w + 4096);                  // 4 MB
    float*  img2  = (float*)(w + 4096 + 4194304);        // 4 MB
    float2* Freq  = (float2*)(w + 4096 + 2 * 4194304);   // 16*129*256*8 = ~4.03 MB

    prep_kernel<<<1, 64, 0, stream>>>(rows, shifts, latent,
                                      W0, b0, W1, b1, W2, b2, W3, b3, bdata);
    zero_kernel<<<IMG_ELEMS / 4 / 256, 256, 0, stream>>>((float4*)img);
    scatter_kernel<<<(NN + 255) / 256, 256, 0, stream>>>(coords, values, Wd, bd,
                                                         bdata, img);
    blur_h_kernel<<<IMG_ELEMS / 256, 256, 0, stream>>>(img, img2);
    blur_w_kernel<<<IMG_ELEMS / 256, 256, 0, stream>>>(img2, img);
    fft_rows_fwd<<<BB * XSZ, 64, 0, stream>>>(img, Freq);
    fft_cols_ctf<<<BB * FREQ_COLS, 64, 0, stream>>>(Freq, ctf);
    fft_rows_inv<<<BB * XSZ, 64, 0, stream>>>(Freq, out);
}

// Round 2
// 533.377 us; speedup vs baseline: 1.0679x; 1.0679x over previous
//
#include <hip/hip_runtime.h>
#include <math.h>

// Problem constants (fixed by reference)
#define BB   16
#define LATD 8
#define NN   500000
#define XSZ  256
#define HALF 128
#define IMG_ELEMS (BB * XSZ * XSZ)          // 1,048,576 floats per image set
#define FREQ_COLS 129                        // XS/2+1

// ---------------------------------------------------------------------------
// K0: per-image prep — rotation rows 0/1, shifts+half, SIREN MLP hidden h[8]
// bdata layout per b (16 floats): R00,R01,R02,R10,R11,R12, sx, sy, h0..h7
// ---------------------------------------------------------------------------
__global__ void prep_kernel(const float* __restrict__ rows,
                            const float* __restrict__ shifts,
                            const float* __restrict__ latent,
                            const float* __restrict__ W0, const float* __restrict__ b0,
                            const float* __restrict__ W1, const float* __restrict__ b1,
                            const float* __restrict__ W2, const float* __restrict__ b2,
                            const float* __restrict__ W3, const float* __restrict__ b3,
                            float* __restrict__ bdata) {
    int b = threadIdx.x;
    if (b >= BB) return;

    float rot  = rows[b * 3 + 0];
    float tilt = rows[b * 3 + 1];
    float psi  = rows[b * 3 + 2];
    float ca, sa, cb, sb, cg, sg;
    sincosf(rot, &sa, &ca);
    sincosf(tilt, &sb, &cb);
    sincosf(psi, &sg, &cg);

    float R00 =  cg * cb * ca - sg * sa;
    float R01 =  cg * cb * sa + sg * ca;
    float R02 = -cg * sb;
    float R10 = -sg * cb * ca - cg * sa;
    float R11 = -sg * cb * sa + cg * ca;
    float R12 =  sg * sb;

    float h[LATD], t[LATD];
    #pragma unroll
    for (int j = 0; j < LATD; ++j) {
        float acc = b0[j];
        #pragma unroll
        for (int l = 0; l < LATD; ++l) acc += latent[b * LATD + l] * W0[l * LATD + j];
        t[j] = acc;
    }
    #pragma unroll
    for (int j = 0; j < LATD; ++j) h[j] = sinf(30.0f * t[j]);

    const float* Ws[3] = {W1, W2, W3};
    const float* bs[3] = {b1, b2, b3};
    for (int L = 0; L < 3; ++L) {
        #pragma unroll
        for (int j = 0; j < LATD; ++j) {
            float acc = bs[L][j];
            #pragma unroll
            for (int l = 0; l < LATD; ++l) acc += h[l] * Ws[L][l * LATD + j];
            t[j] = acc;
        }
        #pragma unroll
        for (int j = 0; j < LATD; ++j) h[j] += sinf(t[j]);
    }

    float* P = bdata + b * 16;
    P[0] = R00; P[1] = R01; P[2] = R02;
    P[3] = R10; P[4] = R11; P[5] = R12;
    P[6] = shifts[b * 2 + 0] + (float)HALF;
    P[7] = shifts[b * 2 + 1] + (float)HALF;
    #pragma unroll
    for (int j = 0; j < LATD; ++j) P[8 + j] = h[j];
}

// ---------------------------------------------------------------------------
// K1: zero the private image copies (float4 stores)
// ---------------------------------------------------------------------------
__global__ void zero_kernel(float4* __restrict__ p, int n4) {
    int i = blockIdx.x * blockDim.x + threadIdx.x;
    if (i < n4) p[i] = make_float4(0.f, 0.f, 0.f, 0.f);
}

// ---------------------------------------------------------------------------
// K2: scatter — per-XCD privatized image copies.
// Each workgroup reads its physical XCC id and accumulates into copies[xcc]
// with WORKGROUP-scope atomics (executed at the local per-XCD L2, no device
// write-through). Cross-workgroup atomicity on the same XCD holds because
// all its workgroups share that TCC; cross-XCD races are excluded by the
// xcc partitioning. End-of-dispatch release writes L2 back for the next
// kernel. Fallback (nc==1): plain device-scope atomicAdd.
// ---------------------------------------------------------------------------
__global__ __launch_bounds__(256) void scatter_kernel(
        const float* __restrict__ coords, const float* __restrict__ values,
        const float* __restrict__ Wd, const float* __restrict__ bd,
        const float* __restrict__ bdata, float* __restrict__ copies, int nc) {
    __shared__ float P[BB * 16];
    P[threadIdx.x] = bdata[threadIdx.x];
    __syncthreads();

    int xcc = 0;
    if (nc == 8) {
        asm volatile("s_getreg_b32 %0, hwreg(HW_REG_XCC_ID)" : "=s"(xcc));
        xcc &= 7;
    }
    float* img = copies + (size_t)xcc * IMG_ELEMS;

    int n = blockIdx.x * 256 + threadIdx.x;
    if (n >= NN) return;

    float cx = coords[n * 3 + 0];
    float cy = coords[n * 3 + 1];
    float cz = coords[n * 3 + 2];
    float base = values[n] + bd[n];

    float wd[LATD];
    #pragma unroll
    for (int l = 0; l < LATD; ++l) wd[l] = Wd[l * NN + n];

    #pragma unroll
    for (int b = 0; b < BB; ++b) {
        const float* Q = &P[b * 16];
        float x = fmaf(Q[0], cx, fmaf(Q[1], cy, fmaf(Q[2], cz, Q[6])));
        float y = fmaf(Q[3], cx, fmaf(Q[4], cy, fmaf(Q[5], cz, Q[7])));
        float px = fminf(fmaxf(rintf(x), 0.f), 255.f);
        float py = fminf(fmaxf(rintf(y), 0.f), 255.f);
        int ipx = (int)px;
        int ipy = (int)py;
        float delta = 0.f;
        #pragma unroll
        for (int l = 0; l < LATD; ++l) delta = fmaf(Q[8 + l], wd[l], delta);
        float v = base + delta;
        int off = (b << 16) | (ipy << 8) | ipx;
        if (nc == 8) {
            __hip_atomic_fetch_add(img + off, v, __ATOMIC_RELAXED,
                                   __HIP_MEMORY_SCOPE_WORKGROUP);
        } else {
            atomicAdd(img + off, v);
        }
    }
}

// ---------------------------------------------------------------------------
// Gaussian 7-tap weights (sigma=1, radius=3, normalized)
// ---------------------------------------------------------------------------
__device__ __constant__ float GW[4] = {0.39905027f, 0.24203623f, 0.05400558f, 0.00443305f};

// ---------------------------------------------------------------------------
// 256-point complex Stockham FFT in LDS, 64 threads, 8 radix-2 stages.
// TW[m] = (cos, sin) of 2*pi*m/256; dir = -1 forward, +1 inverse (unnorm.).
// Result lands back in s0 (8 stages = even # of ping-pongs).
// ---------------------------------------------------------------------------
__device__ __forceinline__ void fft256(float2* s0, float2* s1,
                                       const float2* __restrict__ TW,
                                       int tid, float dir) {
    float2* src = s0;
    float2* dst = s1;
    #pragma unroll
    for (int t = 0; t < 8; ++t) {
        const int s = 1 << t;
        #pragma unroll
        for (int r = 0; r < 2; ++r) {
            int i = tid + (r << 6);          // 0..127
            int q = i & (s - 1);
            int p = i >> t;                  // 0..(128>>t)-1
            float2 a = src[q + s * p];
            float2 b = src[q + s * p + 128];
            int m = p << t;                  // 0..127
            float cs = TW[m].x;
            float sn = dir * TW[m].y;
            float2 sum = make_float2(a.x + b.x, a.y + b.y);
            float dx = a.x - b.x;
            float dy = a.y - b.y;
            float2 tw = make_float2(dx * cs - dy * sn, dx * sn + dy * cs);
            int o = q + ((p * s) << 1);
            dst[o] = sum;
            dst[o + s] = tw;
        }
        __syncthreads();
        float2* tmp = src; src = dst; dst = tmp;
    }
}

__device__ __forceinline__ void fill_tw(float2* TW, int tid) {
    #pragma unroll
    for (int j = 0; j < 2; ++j) {
        int m = tid + (j << 6);              // 0..127
        float sn, cs;
        sincosf(0.0245436926061703f * (float)m, &sn, &cs);  // 2*pi/256 * m
        TW[m] = make_float2(cs, sn);
    }
}

// ---------------------------------------------------------------------------
// K3: fused (sum 8 copies) + x-blur + forward row rFFT.
// Writes Freq transposed: Freq[b][col][y]. Blur along x commutes with the
// later column ops; y-blur is applied in the column kernel (linearity).
// ---------------------------------------------------------------------------
__global__ __launch_bounds__(64) void fft_rows_fwd(const float* __restrict__ copies,
                                                   int nc,
                                                   float2* __restrict__ Freq) {
    __shared__ float2 bufA[256];
    __shared__ float2 bufB[256];
    __shared__ float2 TW[128];
    __shared__ float  rowr[256];
    int tid = threadIdx.x;
    fill_tw(TW, tid);
    int b = blockIdx.x >> 8;
    int y = blockIdx.x & 255;
    size_t rbase = (size_t)blockIdx.x << 8;
    #pragma unroll
    for (int j = 0; j < 4; ++j) {
        int idx = tid + (j << 6);
        float s = 0.f;
        for (int c = 0; c < nc; ++c) s += copies[(size_t)c * IMG_ELEMS + rbase + idx];
        rowr[idx] = s;
    }
    __syncthreads();
    // x-blur (zero-padded SAME)
    #pragma unroll
    for (int j = 0; j < 4; ++j) {
        int idx = tid + (j << 6);
        float acc = GW[0] * rowr[idx];
        #pragma unroll
        for (int t = 1; t <= 3; ++t) {
            if (idx - t >= 0)  acc += GW[t] * rowr[idx - t];
            if (idx + t < 256) acc += GW[t] * rowr[idx + t];
        }
        bufA[idx] = make_float2(acc, 0.f);
    }
    __syncthreads();
    fft256(bufA, bufB, TW, tid, -1.f);
    for (int col = tid; col < FREQ_COLS; col += 64) {
        Freq[((size_t)(b * FREQ_COLS + col) << 8) + y] = bufA[col];
    }
}

// ---------------------------------------------------------------------------
// K4: column pass — y-blur (on complex) + FFT + CTF multiply + inverse FFT.
// ---------------------------------------------------------------------------
__global__ __launch_bounds__(64) void fft_cols_ctf(float2* __restrict__ Freq,
                                                   const float* __restrict__ ctf) {
    __shared__ float2 bufA[256];
    __shared__ float2 bufB[256];
    __shared__ float2 TW[128];
    int tid = threadIdx.x;
    fill_tw(TW, tid);
    int b = blockIdx.x / FREQ_COLS;
    int col = blockIdx.x - b * FREQ_COLS;
    float2* basep = Freq + ((size_t)(b * FREQ_COLS + col) << 8);
    #pragma unroll
    for (int j = 0; j < 4; ++j) {
        int idx = tid + (j << 6);
        bufB[idx] = basep[idx];
    }
    __syncthreads();
    // y-blur (zero-padded SAME), complex
    #pragma unroll
    for (int j = 0; j < 4; ++j) {
        int idx = tid + (j << 6);
        float ax = GW[0] * bufB[idx].x;
        float ay = GW[0] * bufB[idx].y;
        #pragma unroll
        for (int t = 1; t <= 3; ++t) {
            if (idx - t >= 0)  { ax += GW[t] * bufB[idx - t].x; ay += GW[t] * bufB[idx - t].y; }
            if (idx + t < 256) { ax += GW[t] * bufB[idx + t].x; ay += GW[t] * bufB[idx + t].y; }
        }
        bufA[idx] = make_float2(ax, ay);
    }
    __syncthreads();
    fft256(bufA, bufB, TW, tid, -1.f);
    #pragma unroll
    for (int j = 0; j < 4; ++j) {
        int k = tid + (j << 6);
        float c = ctf[(size_t)((b << 8) | k) * FREQ_COLS + col];
        bufA[k].x *= c;
        bufA[k].y *= c;
    }
    __syncthreads();
    fft256(bufA, bufB, TW, tid, +1.f);
    #pragma unroll
    for (int j = 0; j < 4; ++j) {
        int idx = tid + (j << 6);
        basep[idx] = bufA[idx];
    }
}

// ---------------------------------------------------------------------------
// K5: inverse row rFFT — Hermitian-extend 129 -> 256, inverse FFT, real part,
// scale by 1/(256*256)
// ---------------------------------------------------------------------------
__global__ __launch_bounds__(64) void fft_rows_inv(const float2* __restrict__ Freq,
                                                   float* __restrict__ out) {
    __shared__ float2 bufA[256];
    __shared__ float2 bufB[256];
    __shared__ float2 TW[128];
    int tid = threadIdx.x;
    fill_tw(TW, tid);
    int b = blockIdx.x >> 8;
    int y = blockIdx.x & 255;
    for (int col = tid; col < FREQ_COLS; col += 64) {
        bufA[col] = Freq[((size_t)(b * FREQ_COLS + col) << 8) + y];
    }
    __syncthreads();
    for (int k = 129 + tid; k < 256; k += 64) {
        float2 v = bufA[256 - k];
        bufA[k] = make_float2(v.x, -v.y);
    }
    __syncthreads();
    fft256(bufA, bufB, TW, tid, +1.f);
    float* row = out + ((size_t)blockIdx.x << 8);
    const float scale = 1.0f / 65536.0f;
    #pragma unroll
    for (int j = 0; j < 4; ++j) {
        int idx = tid + (j << 6);
        row[idx] = bufA[idx].x * scale;
    }
}

// ---------------------------------------------------------------------------
extern "C" void kernel_launch(void* const* d_in, const int* in_sizes, int n_in,
                              void* d_out, int out_size, void* d_ws, size_t ws_size,
                              hipStream_t stream) {
    const float* rows   = (const float*)d_in[0];
    const float* shifts = (const float*)d_in[1];
    const float* latent = (const float*)d_in[2];
    const float* coords = (const float*)d_in[3];
    const float* values = (const float*)d_in[4];
    const float* W0     = (const float*)d_in[5];
    const float* b0     = (const float*)d_in[6];
    const float* W1     = (const float*)d_in[7];
    const float* b1     = (const float*)d_in[8];
    const float* W2     = (const float*)d_in[9];
    const float* b2     = (const float*)d_in[10];
    const float* W3     = (const float*)d_in[11];
    const float* b3     = (const float*)d_in[12];
    const float* Wd     = (const float*)d_in[13];
    const float* bd     = (const float*)d_in[14];
    const float* ctf    = (const float*)d_in[15];
    float* out = (float*)d_out;

    // workspace layout: bdata (4 KB) | Freq (~4.04 MB) | copies (nc * 4 MB)
    char* w = (char*)d_ws;
    float*  bdata = (float*)(w);
    float2* Freq  = (float2*)(w + 4096);
    size_t freq_bytes = (size_t)BB * FREQ_COLS * 256 * sizeof(float2);
    float*  copies = (float*)(w + 4096 + freq_bytes);

    size_t need8 = 4096 + freq_bytes + 8ull * IMG_ELEMS * sizeof(float);
    int nc = (ws_size >= need8) ? 8 : 1;

    prep_kernel<<<1, 64, 0, stream>>>(rows, shifts, latent,
                                      W0, b0, W1, b1, W2, b2, W3, b3, bdata);
    int n4 = nc * IMG_ELEMS / 4;
    zero_kernel<<<(n4 + 255) / 256, 256, 0, stream>>>((float4*)copies, n4);
    scatter_kernel<<<(NN + 255) / 256, 256, 0, stream>>>(coords, values, Wd, bd,
                                                         bdata, copies, nc);
    fft_rows_fwd<<<BB * XSZ, 64, 0, stream>>>(copies, nc, Freq);
    fft_cols_ctf<<<BB * FREQ_COLS, 64, 0, stream>>>(Freq, ctf);
    fft_rows_inv<<<BB * XSZ, 64, 0, stream>>>(Freq, out);
}

// Round 3
// 259.415 us; speedup vs baseline: 2.1957x; 2.0561x over previous
//
#include <hip/hip_runtime.h>
#include <math.h>

// Problem constants (fixed by reference)
#define BB   16
#define LATD 8
#define NN   500000
#define XSZ  256
#define HALF 128
#define IMG_ELEMS (BB * XSZ * XSZ)          // 1,048,576 floats
#define FREQ_COLS 129                        // XS/2+1
#define NBLK ((NN + 255) / 256)              // 1954 point-blocks

// ---------------------------------------------------------------------------
// K0: per-image prep — rotation rows 0/1, shifts+half, SIREN MLP hidden h[8]
// bdata layout per b (16 floats): R00,R01,R02,R10,R11,R12, sx, sy, h0..h7
// ---------------------------------------------------------------------------
__global__ void prep_kernel(const float* __restrict__ rows,
                            const float* __restrict__ shifts,
                            const float* __restrict__ latent,
                            const float* __restrict__ W0, const float* __restrict__ b0,
                            const float* __restrict__ W1, const float* __restrict__ b1,
                            const float* __restrict__ W2, const float* __restrict__ b2,
                            const float* __restrict__ W3, const float* __restrict__ b3,
                            float* __restrict__ bdata) {
    int b = threadIdx.x;
    if (b >= BB) return;

    float rot  = rows[b * 3 + 0];
    float tilt = rows[b * 3 + 1];
    float psi  = rows[b * 3 + 2];
    float ca, sa, cb, sb, cg, sg;
    sincosf(rot, &sa, &ca);
    sincosf(tilt, &sb, &cb);
    sincosf(psi, &sg, &cg);

    float R00 =  cg * cb * ca - sg * sa;
    float R01 =  cg * cb * sa + sg * ca;
    float R02 = -cg * sb;
    float R10 = -sg * cb * ca - cg * sa;
    float R11 = -sg * cb * sa + cg * ca;
    float R12 =  sg * sb;

    float h[LATD], t[LATD];
    #pragma unroll
    for (int j = 0; j < LATD; ++j) {
        float acc = b0[j];
        #pragma unroll
        for (int l = 0; l < LATD; ++l) acc += latent[b * LATD + l] * W0[l * LATD + j];
        t[j] = acc;
    }
    #pragma unroll
    for (int j = 0; j < LATD; ++j) h[j] = sinf(30.0f * t[j]);

    const float* Ws[3] = {W1, W2, W3};
    const float* bs[3] = {b1, b2, b3};
    for (int L = 0; L < 3; ++L) {
        #pragma unroll
        for (int j = 0; j < LATD; ++j) {
            float acc = bs[L][j];
            #pragma unroll
            for (int l = 0; l < LATD; ++l) acc += h[l] * Ws[L][l * LATD + j];
            t[j] = acc;
        }
        #pragma unroll
        for (int j = 0; j < LATD; ++j) h[j] += sinf(t[j]);
    }

    float* P = bdata + b * 16;
    P[0] = R00; P[1] = R01; P[2] = R02;
    P[3] = R10; P[4] = R11; P[5] = R12;
    P[6] = shifts[b * 2 + 0] + (float)HALF;
    P[7] = shifts[b * 2 + 1] + (float)HALF;
    #pragma unroll
    for (int j = 0; j < LATD; ++j) P[8 + j] = h[j];
}

// Shared projection helper — MUST be bit-identical between count and fill.
__device__ __forceinline__ int2 project_px(const float* __restrict__ Q,
                                           float cx, float cy, float cz) {
    float x = fmaf(Q[0], cx, fmaf(Q[1], cy, fmaf(Q[2], cz, Q[6])));
    float y = fmaf(Q[3], cx, fmaf(Q[4], cy, fmaf(Q[5], cz, Q[7])));
    float px = fminf(fmaxf(rintf(x), 0.f), 255.f);
    float py = fminf(fmaxf(rintf(y), 0.f), 255.f);
    return make_int2((int)px, (int)py);
}

// ---------------------------------------------------------------------------
// K1: count — per-(block,tile) histogram. Tile = (image, 16-row band).
// cnt layout: [block][tile], coalesced writes. No global atomics.
// ---------------------------------------------------------------------------
template<int NB>
__global__ __launch_bounds__(256) void count_kernel(
        const float* __restrict__ coords, const float* __restrict__ bdata,
        unsigned* __restrict__ cnt, int bstart) {
    constexpr int T = NB * 16;
    __shared__ float    P[NB * 16];
    __shared__ unsigned hist[T];
    int tid = threadIdx.x;
    if (tid < NB * 16) P[tid] = bdata[bstart * 16 + tid];
    if (tid < T) hist[tid] = 0;
    __syncthreads();

    int n = blockIdx.x * 256 + tid;
    if (n < NN) {
        float cx = coords[n * 3 + 0];
        float cy = coords[n * 3 + 1];
        float cz = coords[n * 3 + 2];
        #pragma unroll
        for (int bi = 0; bi < NB; ++bi) {
            int2 p = project_px(&P[bi * 16], cx, cy, cz);
            int tile = bi * 16 + (p.y >> 4);
            atomicAdd(&hist[tile], 1u);
        }
    }
    __syncthreads();
    if (tid < T) cnt[(size_t)blockIdx.x * T + tid] = hist[tid];
}

// ---------------------------------------------------------------------------
// K2: column scan — bases[blk][t] = sum_{blk'<blk} cnt[blk'][t]; total[t].
// One block per tile t, 256 threads, chunked Hillis-Steele.
// ---------------------------------------------------------------------------
__global__ __launch_bounds__(256) void scan_cols_kernel(
        const unsigned* __restrict__ cnt, unsigned* __restrict__ bases,
        unsigned* __restrict__ total, int T) {
    __shared__ unsigned s[256];
    int t = blockIdx.x;
    int tid = threadIdx.x;
    unsigned running = 0;
    const int nchunk = (NBLK + 255) >> 8;
    for (int c = 0; c < nchunk; ++c) {
        int blk = (c << 8) + tid;
        unsigned v = (blk < NBLK) ? cnt[(size_t)blk * T + t] : 0u;
        s[tid] = v;
        __syncthreads();
        unsigned x = v;
        for (int off = 1; off < 256; off <<= 1) {
            unsigned y = (tid >= off) ? s[tid - off] : 0u;
            __syncthreads();
            x += y;
            s[tid] = x;
            __syncthreads();
        }
        if (blk < NBLK) bases[(size_t)blk * T + t] = running + x - v;
        unsigned chunk_total = s[255];
        __syncthreads();
        running += chunk_total;
    }
    if (tid == 0) total[t] = running;
}

// K3: exclusive scan of tile totals -> tileBase. Single block.
__global__ __launch_bounds__(256) void scan_small_kernel(
        const unsigned* __restrict__ total, unsigned* __restrict__ tileBase, int T) {
    __shared__ unsigned s[256];
    int tid = threadIdx.x;
    unsigned v = (tid < T) ? total[tid] : 0u;
    s[tid] = v;
    __syncthreads();
    unsigned x = v;
    for (int off = 1; off < 256; off <<= 1) {
        unsigned y = (tid >= off) ? s[tid - off] : 0u;
        __syncthreads();
        x += y;
        s[tid] = x;
        __syncthreads();
    }
    if (tid < T) tileBase[tid] = x - v;
}

// ---------------------------------------------------------------------------
// K4: fill — recompute projection + delta, rank via LDS fetch_add, stage
// tile-ordered in LDS, write coalesced {off12|, value} records to buckets.
// ---------------------------------------------------------------------------
template<int NB>
__global__ __launch_bounds__(256) void fill_kernel(
        const float* __restrict__ coords, const float* __restrict__ values,
        const float* __restrict__ Wd, const float* __restrict__ bd,
        const float* __restrict__ bdata, const unsigned* __restrict__ bases,
        const unsigned* __restrict__ tileBase, uint2* __restrict__ bucket,
        int bstart) {
    constexpr int T = NB * 16;
    __shared__ float    P[NB * 16];
    __shared__ unsigned hist[T];
    __shared__ unsigned sc[256];
    __shared__ unsigned lbase[T];
    __shared__ unsigned gadj[T];      // tileBase + blockBase - lbase
    __shared__ uint2    stage[256 * NB];

    int tid = threadIdx.x;
    int blk = blockIdx.x;
    if (tid < NB * 16) P[tid] = bdata[bstart * 16 + tid];
    if (tid < T) hist[tid] = 0;
    __syncthreads();

    int n = blk * 256 + tid;
    bool active = (n < NN);

    unsigned word[NB];
    unsigned rank[NB];
    float    fval[NB];
    if (active) {
        float cx = coords[n * 3 + 0];
        float cy = coords[n * 3 + 1];
        float cz = coords[n * 3 + 2];
        float base = values[n] + bd[n];
        float wd[LATD];
        #pragma unroll
        for (int l = 0; l < LATD; ++l) wd[l] = Wd[l * NN + n];
        #pragma unroll
        for (int bi = 0; bi < NB; ++bi) {
            const float* Q = &P[bi * 16];
            int2 p = project_px(Q, cx, cy, cz);
            float delta = 0.f;
            #pragma unroll
            for (int l = 0; l < LATD; ++l) delta = fmaf(Q[8 + l], wd[l], delta);
            int tile = bi * 16 + (p.y >> 4);
            int off12 = ((p.y & 15) << 8) | p.x;
            word[bi] = (unsigned)(off12 | (tile << 12));
            fval[bi] = base + delta;
            rank[bi] = atomicAdd(&hist[tile], 1u);
        }
    }
    __syncthreads();

    // exclusive scan of hist -> lbase
    unsigned v = (tid < T) ? hist[tid] : 0u;
    sc[tid] = v;
    __syncthreads();
    unsigned x = v;
    for (int off = 1; off < 256; off <<= 1) {
        unsigned y = (tid >= off) ? sc[tid - off] : 0u;
        __syncthreads();
        x += y;
        sc[tid] = x;
        __syncthreads();
    }
    if (tid < T) {
        lbase[tid] = x - v;
        gadj[tid]  = tileBase[tid] + bases[(size_t)blk * T + tid] - (x - v);
    }
    __syncthreads();

    if (active) {
        #pragma unroll
        for (int bi = 0; bi < NB; ++bi) {
            unsigned t = word[bi] >> 12;
            stage[lbase[t] + rank[bi]] = make_uint2(word[bi], __float_as_uint(fval[bi]));
        }
    }
    __syncthreads();

    int nactive = NN - blk * 256;
    if (nactive > 256) nactive = 256;
    int tot = nactive * NB;
    for (int i = tid; i < tot; i += 256) {
        uint2 e = stage[i];
        unsigned t = e.x >> 12;
        bucket[gadj[t] + i] = make_uint2(e.x & 0xFFFu, e.y);
    }
}

// ---------------------------------------------------------------------------
// K5: accum — one block per tile; stream its bucket segment, LDS atomicAdd,
// write the 16-row band once (no zeroing of img needed: full overwrite).
// ---------------------------------------------------------------------------
__global__ __launch_bounds__(256) void accum_kernel(
        const uint2* __restrict__ bucket, const unsigned* __restrict__ tileBase,
        const unsigned* __restrict__ total, float* __restrict__ img, int bstart) {
    __shared__ float tile[4096];
    int t = blockIdx.x;
    int tid = threadIdx.x;
    for (int i = tid; i < 4096; i += 256) tile[i] = 0.f;
    __syncthreads();
    unsigned s0 = tileBase[t];
    unsigned cntt = total[t];
    for (unsigned i = tid; i < cntt; i += 256) {
        uint2 e = bucket[s0 + i];
        atomicAdd(&tile[e.x & 4095u], __uint_as_float(e.y));
    }
    __syncthreads();
    int b = bstart + (t >> 4);
    int band = t & 15;
    float4* dst = (float4*)(img + ((size_t)b << 16) + (band << 12));
    const float4* src = (const float4*)tile;
    for (int i = tid; i < 1024; i += 256) dst[i] = src[i];
}

// ---------------------------------------------------------------------------
// Fallback: device-scope atomic scatter (R1 path) + zero
// ---------------------------------------------------------------------------
__global__ void zero_kernel(float4* __restrict__ p, int n4) {
    int i = blockIdx.x * blockDim.x + threadIdx.x;
    if (i < n4) p[i] = make_float4(0.f, 0.f, 0.f, 0.f);
}

__global__ __launch_bounds__(256) void scatter_atomic_kernel(
        const float* __restrict__ coords, const float* __restrict__ values,
        const float* __restrict__ Wd, const float* __restrict__ bd,
        const float* __restrict__ bdata, float* __restrict__ img) {
    __shared__ float P[BB * 16];
    P[threadIdx.x] = bdata[threadIdx.x];
    __syncthreads();
    int n = blockIdx.x * 256 + threadIdx.x;
    if (n >= NN) return;
    float cx = coords[n * 3 + 0];
    float cy = coords[n * 3 + 1];
    float cz = coords[n * 3 + 2];
    float base = values[n] + bd[n];
    float wd[LATD];
    #pragma unroll
    for (int l = 0; l < LATD; ++l) wd[l] = Wd[l * NN + n];
    #pragma unroll
    for (int b = 0; b < BB; ++b) {
        const float* Q = &P[b * 16];
        int2 p = project_px(Q, cx, cy, cz);
        float delta = 0.f;
        #pragma unroll
        for (int l = 0; l < LATD; ++l) delta = fmaf(Q[8 + l], wd[l], delta);
        atomicAdd(img + ((b << 16) | (p.y << 8) | p.x), base + delta);
    }
}

// ---------------------------------------------------------------------------
// Gaussian 7-tap weights (sigma=1, radius=3, normalized)
// ---------------------------------------------------------------------------
__device__ __constant__ float GW[4] = {0.39905027f, 0.24203623f, 0.05400558f, 0.00443305f};

// ---------------------------------------------------------------------------
// 256-point complex Stockham FFT in LDS, 64 threads, 8 radix-2 stages.
// ---------------------------------------------------------------------------
__device__ __forceinline__ void fft256(float2* s0, float2* s1,
                                       const float2* __restrict__ TW,
                                       int tid, float dir) {
    float2* src = s0;
    float2* dst = s1;
    #pragma unroll
    for (int t = 0; t < 8; ++t) {
        const int s = 1 << t;
        #pragma unroll
        for (int r = 0; r < 2; ++r) {
            int i = tid + (r << 6);
            int q = i & (s - 1);
            int p = i >> t;
            float2 a = src[q + s * p];
            float2 b = src[q + s * p + 128];
            int m = p << t;
            float cs = TW[m].x;
            float sn = dir * TW[m].y;
            float2 sum = make_float2(a.x + b.x, a.y + b.y);
            float dx = a.x - b.x;
            float dy = a.y - b.y;
            float2 tw = make_float2(dx * cs - dy * sn, dx * sn + dy * cs);
            int o = q + ((p * s) << 1);
            dst[o] = sum;
            dst[o + s] = tw;
        }
        __syncthreads();
        float2* tmp = src; src = dst; dst = tmp;
    }
}

__device__ __forceinline__ void fill_tw(float2* TW, int tid) {
    #pragma unroll
    for (int j = 0; j < 2; ++j) {
        int m = tid + (j << 6);
        float sn, cs;
        sincosf(0.0245436926061703f * (float)m, &sn, &cs);
        TW[m] = make_float2(cs, sn);
    }
}

// K6: x-blur + forward row rFFT; writes Freq transposed Freq[b][col][y]
__global__ __launch_bounds__(64) void fft_rows_fwd(const float* __restrict__ img,
                                                   float2* __restrict__ Freq) {
    __shared__ float2 bufA[256];
    __shared__ float2 bufB[256];
    __shared__ float2 TW[128];
    __shared__ float  rowr[256];
    int tid = threadIdx.x;
    fill_tw(TW, tid);
    int b = blockIdx.x >> 8;
    int y = blockIdx.x & 255;
    const float* row = img + ((size_t)blockIdx.x << 8);
    #pragma unroll
    for (int j = 0; j < 4; ++j) {
        int idx = tid + (j << 6);
        rowr[idx] = row[idx];
    }
    __syncthreads();
    #pragma unroll
    for (int j = 0; j < 4; ++j) {
        int idx = tid + (j << 6);
        float acc = GW[0] * rowr[idx];
        #pragma unroll
        for (int t = 1; t <= 3; ++t) {
            if (idx - t >= 0)  acc += GW[t] * rowr[idx - t];
            if (idx + t < 256) acc += GW[t] * rowr[idx + t];
        }
        bufA[idx] = make_float2(acc, 0.f);
    }
    __syncthreads();
    fft256(bufA, bufB, TW, tid, -1.f);
    for (int col = tid; col < FREQ_COLS; col += 64) {
        Freq[((size_t)(b * FREQ_COLS + col) << 8) + y] = bufA[col];
    }
}

// K7: column pass — y-blur (complex) + FFT + CTF + inverse FFT
__global__ __launch_bounds__(64) void fft_cols_ctf(float2* __restrict__ Freq,
                                                   const float* __restrict__ ctf) {
    __shared__ float2 bufA[256];
    __shared__ float2 bufB[256];
    __shared__ float2 TW[128];
    int tid = threadIdx.x;
    fill_tw(TW, tid);
    int b = blockIdx.x / FREQ_COLS;
    int col = blockIdx.x - b * FREQ_COLS;
    float2* basep = Freq + ((size_t)(b * FREQ_COLS + col) << 8);
    #pragma unroll
    for (int j = 0; j < 4; ++j) {
        int idx = tid + (j << 6);
        bufB[idx] = basep[idx];
    }
    __syncthreads();
    #pragma unroll
    for (int j = 0; j < 4; ++j) {
        int idx = tid + (j << 6);
        float ax = GW[0] * bufB[idx].x;
        float ay = GW[0] * bufB[idx].y;
        #pragma unroll
        for (int t = 1; t <= 3; ++t) {
            if (idx - t >= 0)  { ax += GW[t] * bufB[idx - t].x; ay += GW[t] * bufB[idx - t].y; }
            if (idx + t < 256) { ax += GW[t] * bufB[idx + t].x; ay += GW[t] * bufB[idx + t].y; }
        }
        bufA[idx] = make_float2(ax, ay);
    }
    __syncthreads();
    fft256(bufA, bufB, TW, tid, -1.f);
    #pragma unroll
    for (int j = 0; j < 4; ++j) {
        int k = tid + (j << 6);
        float c = ctf[(size_t)((b << 8) | k) * FREQ_COLS + col];
        bufA[k].x *= c;
        bufA[k].y *= c;
    }
    __syncthreads();
    fft256(bufA, bufB, TW, tid, +1.f);
    #pragma unroll
    for (int j = 0; j < 4; ++j) {
        int idx = tid + (j << 6);
        basep[idx] = bufA[idx];
    }
}

// K8: Hermitian-extend + inverse row FFT + scale
__global__ __launch_bounds__(64) void fft_rows_inv(const float2* __restrict__ Freq,
                                                   float* __restrict__ out) {
    __shared__ float2 bufA[256];
    __shared__ float2 bufB[256];
    __shared__ float2 TW[128];
    int tid = threadIdx.x;
    fill_tw(TW, tid);
    int b = blockIdx.x >> 8;
    int y = blockIdx.x & 255;
    for (int col = tid; col < FREQ_COLS; col += 64) {
        bufA[col] = Freq[((size_t)(b * FREQ_COLS + col) << 8) + y];
    }
    __syncthreads();
    for (int k = 129 + tid; k < 256; k += 64) {
        float2 v = bufA[256 - k];
        bufA[k] = make_float2(v.x, -v.y);
    }
    __syncthreads();
    fft256(bufA, bufB, TW, tid, +1.f);
    float* row = out + ((size_t)blockIdx.x << 8);
    const float scale = 1.0f / 65536.0f;
    #pragma unroll
    for (int j = 0; j < 4; ++j) {
        int idx = tid + (j << 6);
        row[idx] = bufA[idx].x * scale;
    }
}

// ---------------------------------------------------------------------------
template<int NB>
static void run_binned(const float* coords, const float* values, const float* Wd,
                       const float* bd, float* bdata, unsigned* cnt, unsigned* bases,
                       unsigned* total, unsigned* tileBase, uint2* bucket, float* img,
                       hipStream_t stream) {
    constexpr int T = NB * 16;
    const int NG = BB / NB;
    for (int g = 0; g < NG; ++g) {
        int bstart = g * NB;
        count_kernel<NB><<<NBLK, 256, 0, stream>>>(coords, bdata, cnt, bstart);
        scan_cols_kernel<<<T, 256, 0, stream>>>(cnt, bases, total, T);
        scan_small_kernel<<<1, 256, 0, stream>>>(total, tileBase, T);
        fill_kernel<NB><<<NBLK, 256, 0, stream>>>(coords, values, Wd, bd, bdata,
                                                  bases, tileBase, bucket, bstart);
        accum_kernel<<<T, 256, 0, stream>>>(bucket, tileBase, total, img, bstart);
    }
}

extern "C" void kernel_launch(void* const* d_in, const int* in_sizes, int n_in,
                              void* d_out, int out_size, void* d_ws, size_t ws_size,
                              hipStream_t stream) {
    const float* rows   = (const float*)d_in[0];
    const float* shifts = (const float*)d_in[1];
    const float* latent = (const float*)d_in[2];
    const float* coords = (const float*)d_in[3];
    const float* values = (const float*)d_in[4];
    const float* W0     = (const float*)d_in[5];
    const float* b0     = (const float*)d_in[6];
    const float* W1     = (const float*)d_in[7];
    const float* b1     = (const float*)d_in[8];
    const float* W2     = (const float*)d_in[9];
    const float* b2     = (const float*)d_in[10];
    const float* W3     = (const float*)d_in[11];
    const float* b3     = (const float*)d_in[12];
    const float* Wd     = (const float*)d_in[13];
    const float* bd     = (const float*)d_in[14];
    const float* ctf    = (const float*)d_in[15];
    float* out = (float*)d_out;

    // Workspace layout
    char* w = (char*)d_ws;
    size_t off = 0;
    float* bdata = (float*)(w + off);  off += 4096;
    float* img   = (float*)(w + off);  off += (size_t)IMG_ELEMS * 4;
    float2* Freq = (float2*)(w + off); off += (size_t)BB * FREQ_COLS * 256 * 8;
    unsigned* cnt   = (unsigned*)(w + off); off += (size_t)NBLK * 256 * 4;
    unsigned* bases = (unsigned*)(w + off); off += (size_t)NBLK * 256 * 4;
    unsigned* total = (unsigned*)(w + off); off += 1024;
    unsigned* tileBase = (unsigned*)(w + off); off += 1024;
    uint2* bucket = (uint2*)(w + off);
    size_t fixed = off;

    int NB = 0;
    if      (ws_size >= fixed + (size_t)NN * 16 * 8) NB = 16;
    else if (ws_size >= fixed + (size_t)NN *  8 * 8) NB = 8;
    else if (ws_size >= fixed + (size_t)NN *  4 * 8) NB = 4;
    else if (ws_size >= fixed + (size_t)NN *  2 * 8) NB = 2;
    else if (ws_size >= fixed + (size_t)NN *  1 * 8) NB = 1;

    prep_kernel<<<1, 64, 0, stream>>>(rows, shifts, latent,
                                      W0, b0, W1, b1, W2, b2, W3, b3, bdata);

    switch (NB) {
    case 16: run_binned<16>(coords, values, Wd, bd, bdata, cnt, bases, total, tileBase, bucket, img, stream); break;
    case 8:  run_binned<8> (coords, values, Wd, bd, bdata, cnt, bases, total, tileBase, bucket, img, stream); break;
    case 4:  run_binned<4> (coords, values, Wd, bd, bdata, cnt, bases, total, tileBase, bucket, img, stream); break;
    case 2:  run_binned<2> (coords, values, Wd, bd, bdata, cnt, bases, total, tileBase, bucket, img, stream); break;
    case 1:  run_binned<1> (coords, values, Wd, bd, bdata, cnt, bases, total, tileBase, bucket, img, stream); break;
    default: {
        int n4 = IMG_ELEMS / 4;
        zero_kernel<<<(n4 + 255) / 256, 256, 0, stream>>>((float4*)img, n4);
        scatter_atomic_kernel<<<NBLK, 256, 0, stream>>>(coords, values, Wd, bd, bdata, img);
    } break;
    }

    fft_rows_fwd<<<BB * XSZ, 64, 0, stream>>>(img, Freq);
    fft_cols_ctf<<<BB * FREQ_COLS, 64, 0, stream>>>(Freq, ctf);
    fft_rows_inv<<<BB * XSZ, 64, 0, stream>>>(Freq, out);
}

// Round 4
// 247.455 us; speedup vs baseline: 2.3018x; 1.0483x over previous
//
#include <hip/hip_runtime.h>
#include <math.h>

// Problem constants (fixed by reference)
#define BB   16
#define LATD 8
#define NN   500000
#define XSZ  256
#define HALF 128
#define IMG_ELEMS (BB * XSZ * XSZ)          // 1,048,576 floats
#define FREQ_COLS 129                        // XS/2+1
#define NBLK ((NN + 255) / 256)              // 1954 point-blocks

// ---------------------------------------------------------------------------
// wave64 inclusive scan (shuffle-based, no barriers)
// ---------------------------------------------------------------------------
__device__ __forceinline__ unsigned wave_incl_scan(unsigned x, int lane) {
    #pragma unroll
    for (int d = 1; d < 64; d <<= 1) {
        unsigned y = __shfl_up(x, d, 64);
        if (lane >= d) x += y;
    }
    return x;
}

// ---------------------------------------------------------------------------
// K0: per-image prep — rotation rows 0/1, shifts+half, SIREN MLP hidden h[8]
// bdata layout per b (16 floats): R00,R01,R02,R10,R11,R12, sx, sy, h0..h7
// ---------------------------------------------------------------------------
__global__ void prep_kernel(const float* __restrict__ rows,
                            const float* __restrict__ shifts,
                            const float* __restrict__ latent,
                            const float* __restrict__ W0, const float* __restrict__ b0,
                            const float* __restrict__ W1, const float* __restrict__ b1,
                            const float* __restrict__ W2, const float* __restrict__ b2,
                            const float* __restrict__ W3, const float* __restrict__ b3,
                            float* __restrict__ bdata) {
    int b = threadIdx.x;
    if (b >= BB) return;

    float rot  = rows[b * 3 + 0];
    float tilt = rows[b * 3 + 1];
    float psi  = rows[b * 3 + 2];
    float ca, sa, cb, sb, cg, sg;
    sincosf(rot, &sa, &ca);
    sincosf(tilt, &sb, &cb);
    sincosf(psi, &sg, &cg);

    float R00 =  cg * cb * ca - sg * sa;
    float R01 =  cg * cb * sa + sg * ca;
    float R02 = -cg * sb;
    float R10 = -sg * cb * ca - cg * sa;
    float R11 = -sg * cb * sa + cg * ca;
    float R12 =  sg * sb;

    float h[LATD], t[LATD];
    #pragma unroll
    for (int j = 0; j < LATD; ++j) {
        float acc = b0[j];
        #pragma unroll
        for (int l = 0; l < LATD; ++l) acc += latent[b * LATD + l] * W0[l * LATD + j];
        t[j] = acc;
    }
    #pragma unroll
    for (int j = 0; j < LATD; ++j) h[j] = sinf(30.0f * t[j]);

    const float* Ws[3] = {W1, W2, W3};
    const float* bs[3] = {b1, b2, b3};
    for (int L = 0; L < 3; ++L) {
        #pragma unroll
        for (int j = 0; j < LATD; ++j) {
            float acc = bs[L][j];
            #pragma unroll
            for (int l = 0; l < LATD; ++l) acc += h[l] * Ws[L][l * LATD + j];
            t[j] = acc;
        }
        #pragma unroll
        for (int j = 0; j < LATD; ++j) h[j] += sinf(t[j]);
    }

    float* P = bdata + b * 16;
    P[0] = R00; P[1] = R01; P[2] = R02;
    P[3] = R10; P[4] = R11; P[5] = R12;
    P[6] = shifts[b * 2 + 0] + (float)HALF;
    P[7] = shifts[b * 2 + 1] + (float)HALF;
    #pragma unroll
    for (int j = 0; j < LATD; ++j) P[8 + j] = h[j];
}

// Shared projection helper — MUST be bit-identical between count and fill.
__device__ __forceinline__ int2 project_px(const float* __restrict__ Q,
                                           float cx, float cy, float cz) {
    float x = fmaf(Q[0], cx, fmaf(Q[1], cy, fmaf(Q[2], cz, Q[6])));
    float y = fmaf(Q[3], cx, fmaf(Q[4], cy, fmaf(Q[5], cz, Q[7])));
    float px = fminf(fmaxf(rintf(x), 0.f), 255.f);
    float py = fminf(fmaxf(rintf(y), 0.f), 255.f);
    return make_int2((int)px, (int)py);
}

// ---------------------------------------------------------------------------
// K1: count — per-(block,tile) histogram. Tile = (image, 16-row band).
// ---------------------------------------------------------------------------
template<int NB>
__global__ __launch_bounds__(256) void count_kernel(
        const float* __restrict__ coords, const float* __restrict__ bdata,
        unsigned* __restrict__ cnt, int bstart) {
    constexpr int T = NB * 16;
    __shared__ float    P[NB * 16];
    __shared__ unsigned hist[T];
    int tid = threadIdx.x;
    if (tid < NB * 16) P[tid] = bdata[bstart * 16 + tid];
    if (tid < T) hist[tid] = 0;
    __syncthreads();

    int n = blockIdx.x * 256 + tid;
    if (n < NN) {
        float cx = coords[n * 3 + 0];
        float cy = coords[n * 3 + 1];
        float cz = coords[n * 3 + 2];
        #pragma unroll
        for (int bi = 0; bi < NB; ++bi) {
            int2 p = project_px(&P[bi * 16], cx, cy, cz);
            int tile = bi * 16 + (p.y >> 4);
            atomicAdd(&hist[tile], 1u);
        }
    }
    __syncthreads();
    if (tid < T) cnt[(size_t)blockIdx.x * T + tid] = hist[tid];
}

// ---------------------------------------------------------------------------
// K2: column scan — bases[blk][t] = sum_{blk'<blk} cnt[blk'][t]; total[t].
// One block per tile t, 256 threads, wave-shuffle scan, 1 barrier/chunk.
// ---------------------------------------------------------------------------
__global__ __launch_bounds__(256) void scan_cols_kernel(
        const unsigned* __restrict__ cnt, unsigned* __restrict__ bases,
        unsigned* __restrict__ total, int T) {
    __shared__ unsigned wsum[2][4];
    int t = blockIdx.x;
    int tid = threadIdx.x;
    int lane = tid & 63;
    int wv = tid >> 6;
    unsigned running = 0;
    const int nchunk = (NBLK + 255) >> 8;
    for (int c = 0; c < nchunk; ++c) {
        int blk = (c << 8) + tid;
        unsigned v = (blk < NBLK) ? cnt[(size_t)blk * T + t] : 0u;
        unsigned s = wave_incl_scan(v, lane);
        if (lane == 63) wsum[c & 1][wv] = s;
        __syncthreads();
        unsigned off = 0, tot = 0;
        #pragma unroll
        for (int i = 0; i < 4; ++i) {
            unsigned u = wsum[c & 1][i];
            if (i < wv) off += u;
            tot += u;
        }
        if (blk < NBLK) bases[(size_t)blk * T + t] = running + s + off - v;
        running += tot;
    }
    if (tid == 0) total[t] = running;
}

// K3: exclusive scan of tile totals -> tileBase. Single block, shuffle scan.
__global__ __launch_bounds__(256) void scan_small_kernel(
        const unsigned* __restrict__ total, unsigned* __restrict__ tileBase, int T) {
    __shared__ unsigned wsum[4];
    int tid = threadIdx.x;
    int lane = tid & 63;
    int wv = tid >> 6;
    unsigned v = (tid < T) ? total[tid] : 0u;
    unsigned s = wave_incl_scan(v, lane);
    if (lane == 63) wsum[wv] = s;
    __syncthreads();
    unsigned off = 0;
    #pragma unroll
    for (int i = 0; i < 4; ++i) { unsigned u = wsum[i]; if (i < wv) off += u; }
    if (tid < T) tileBase[tid] = s + off - v;
}

// ---------------------------------------------------------------------------
// K4: fill — recompute projection + delta, rank via LDS fetch_add, stage
// tile-ordered in LDS, write coalesced {off12, value} records to buckets.
// ---------------------------------------------------------------------------
template<int NB>
__global__ __launch_bounds__(256) void fill_kernel(
        const float* __restrict__ coords, const float* __restrict__ values,
        const float* __restrict__ Wd, const float* __restrict__ bd,
        const float* __restrict__ bdata, const unsigned* __restrict__ bases,
        const unsigned* __restrict__ tileBase, uint2* __restrict__ bucket,
        int bstart) {
    constexpr int T = NB * 16;
    __shared__ float    P[NB * 16];
    __shared__ unsigned hist[T];
    __shared__ unsigned wsum[4];
    __shared__ unsigned lbase[T];
    __shared__ unsigned gadj[T];      // tileBase + blockBase - lbase
    __shared__ uint2    stage[256 * NB];

    int tid = threadIdx.x;
    int blk = blockIdx.x;
    int lane = tid & 63;
    int wv = tid >> 6;
    if (tid < NB * 16) P[tid] = bdata[bstart * 16 + tid];
    if (tid < T) hist[tid] = 0;
    __syncthreads();

    int n = blk * 256 + tid;
    bool active = (n < NN);

    unsigned word[NB];
    unsigned rank[NB];
    float    fval[NB];
    if (active) {
        float cx = coords[n * 3 + 0];
        float cy = coords[n * 3 + 1];
        float cz = coords[n * 3 + 2];
        float base = values[n] + bd[n];
        float wd[LATD];
        #pragma unroll
        for (int l = 0; l < LATD; ++l) wd[l] = Wd[l * NN + n];
        #pragma unroll
        for (int bi = 0; bi < NB; ++bi) {
            const float* Q = &P[bi * 16];
            int2 p = project_px(Q, cx, cy, cz);
            float delta = 0.f;
            #pragma unroll
            for (int l = 0; l < LATD; ++l) delta = fmaf(Q[8 + l], wd[l], delta);
            int tile = bi * 16 + (p.y >> 4);
            int off12 = ((p.y & 15) << 8) | p.x;
            word[bi] = (unsigned)(off12 | (tile << 12));
            fval[bi] = base + delta;
            rank[bi] = atomicAdd(&hist[tile], 1u);
        }
    }
    __syncthreads();

    // exclusive scan of hist (T<=256 elements) via wave shuffles
    unsigned v = (tid < T) ? hist[tid] : 0u;
    unsigned s = wave_incl_scan(v, lane);
    if (lane == 63) wsum[wv] = s;
    __syncthreads();
    unsigned off = 0;
    #pragma unroll
    for (int i = 0; i < 4; ++i) { unsigned u = wsum[i]; if (i < wv) off += u; }
    unsigned excl = s + off - v;
    if (tid < T) {
        lbase[tid] = excl;
        gadj[tid]  = tileBase[tid] + bases[(size_t)blk * T + tid] - excl;
    }
    __syncthreads();

    if (active) {
        #pragma unroll
        for (int bi = 0; bi < NB; ++bi) {
            unsigned t = word[bi] >> 12;
            stage[lbase[t] + rank[bi]] = make_uint2(word[bi], __float_as_uint(fval[bi]));
        }
    }
    __syncthreads();

    int nactive = NN - blk * 256;
    if (nactive > 256) nactive = 256;
    int tot = nactive * NB;
    for (int i = tid; i < tot; i += 256) {
        uint2 e = stage[i];
        unsigned t = e.x >> 12;
        bucket[gadj[t] + i] = make_uint2(e.x & 0xFFFu, e.y);
    }
}

// ---------------------------------------------------------------------------
// K5: accum — one block of 1024 threads per tile; stream bucket segment with
// 4-way unrolled independent loads (latency hiding), LDS atomicAdd, write
// the 16-row band once.
// ---------------------------------------------------------------------------
__global__ __launch_bounds__(1024) void accum_kernel(
        const uint2* __restrict__ bucket, const unsigned* __restrict__ tileBase,
        const unsigned* __restrict__ total, float* __restrict__ img, int bstart) {
    __shared__ float tile[4096];
    int t = blockIdx.x;
    int tid = threadIdx.x;
    for (int i = tid; i < 4096; i += 1024) tile[i] = 0.f;
    __syncthreads();
    unsigned s0 = tileBase[t];
    unsigned cntt = total[t];
    unsigned nchunk = (cntt + 4095) >> 12;
    for (unsigned c = 0; c < nchunk; ++c) {
        unsigned base = s0 + (c << 12);
        unsigned rem  = cntt - (c << 12);       // entries left in this chunk view
        uint2 e[4];
        unsigned idx[4];
        #pragma unroll
        for (int k = 0; k < 4; ++k) {
            idx[k] = (unsigned)(k << 10) + tid;
            if (idx[k] < rem) e[k] = bucket[base + idx[k]];
        }
        #pragma unroll
        for (int k = 0; k < 4; ++k) {
            if (idx[k] < rem)
                atomicAdd(&tile[e[k].x & 4095u], __uint_as_float(e[k].y));
        }
    }
    __syncthreads();
    int b = bstart + (t >> 4);
    int band = t & 15;
    float4* dst = (float4*)(img + ((size_t)b << 16) + (band << 12));
    const float4* src = (const float4*)tile;
    for (int i = tid; i < 1024; i += 1024) dst[i] = src[i];
}

// ---------------------------------------------------------------------------
// Fallback: device-scope atomic scatter (R1 path) + zero
// ---------------------------------------------------------------------------
__global__ void zero_kernel(float4* __restrict__ p, int n4) {
    int i = blockIdx.x * blockDim.x + threadIdx.x;
    if (i < n4) p[i] = make_float4(0.f, 0.f, 0.f, 0.f);
}

__global__ __launch_bounds__(256) void scatter_atomic_kernel(
        const float* __restrict__ coords, const float* __restrict__ values,
        const float* __restrict__ Wd, const float* __restrict__ bd,
        const float* __restrict__ bdata, float* __restrict__ img) {
    __shared__ float P[BB * 16];
    P[threadIdx.x] = bdata[threadIdx.x];
    __syncthreads();
    int n = blockIdx.x * 256 + threadIdx.x;
    if (n >= NN) return;
    float cx = coords[n * 3 + 0];
    float cy = coords[n * 3 + 1];
    float cz = coords[n * 3 + 2];
    float base = values[n] + bd[n];
    float wd[LATD];
    #pragma unroll
    for (int l = 0; l < LATD; ++l) wd[l] = Wd[l * NN + n];
    #pragma unroll
    for (int b = 0; b < BB; ++b) {
        const float* Q = &P[b * 16];
        int2 p = project_px(Q, cx, cy, cz);
        float delta = 0.f;
        #pragma unroll
        for (int l = 0; l < LATD; ++l) delta = fmaf(Q[8 + l], wd[l], delta);
        atomicAdd(img + ((b << 16) | (p.y << 8) | p.x), base + delta);
    }
}

// ---------------------------------------------------------------------------
// Gaussian 7-tap weights (sigma=1, radius=3, normalized)
// ---------------------------------------------------------------------------
__device__ __constant__ float GW[4] = {0.39905027f, 0.24203623f, 0.05400558f, 0.00443305f};

// ---------------------------------------------------------------------------
// 256-point complex Stockham FFT in LDS, 64 threads, 8 radix-2 stages.
// ---------------------------------------------------------------------------
__device__ __forceinline__ void fft256(float2* s0, float2* s1,
                                       const float2* __restrict__ TW,
                                       int tid, float dir) {
    float2* src = s0;
    float2* dst = s1;
    #pragma unroll
    for (int t = 0; t < 8; ++t) {
        const int s = 1 << t;
        #pragma unroll
        for (int r = 0; r < 2; ++r) {
            int i = tid + (r << 6);
            int q = i & (s - 1);
            int p = i >> t;
            float2 a = src[q + s * p];
            float2 b = src[q + s * p + 128];
            int m = p << t;
            float cs = TW[m].x;
            float sn = dir * TW[m].y;
            float2 sum = make_float2(a.x + b.x, a.y + b.y);
            float dx = a.x - b.x;
            float dy = a.y - b.y;
            float2 tw = make_float2(dx * cs - dy * sn, dx * sn + dy * cs);
            int o = q + ((p * s) << 1);
            dst[o] = sum;
            dst[o + s] = tw;
        }
        __syncthreads();
        float2* tmp = src; src = dst; dst = tmp;
    }
}

__device__ __forceinline__ void fill_tw(float2* TW, int tid) {
    #pragma unroll
    for (int j = 0; j < 2; ++j) {
        int m = tid + (j << 6);
        float sn, cs;
        sincosf(0.0245436926061703f * (float)m, &sn, &cs);
        TW[m] = make_float2(cs, sn);
    }
}

// K6: x-blur + forward row rFFT; writes Freq transposed Freq[b][col][y]
__global__ __launch_bounds__(64) void fft_rows_fwd(const float* __restrict__ img,
                                                   float2* __restrict__ Freq) {
    __shared__ float2 bufA[256];
    __shared__ float2 bufB[256];
    __shared__ float2 TW[128];
    __shared__ float  rowr[256];
    int tid = threadIdx.x;
    fill_tw(TW, tid);
    int b = blockIdx.x >> 8;
    int y = blockIdx.x & 255;
    const float* row = img + ((size_t)blockIdx.x << 8);
    #pragma unroll
    for (int j = 0; j < 4; ++j) {
        int idx = tid + (j << 6);
        rowr[idx] = row[idx];
    }
    __syncthreads();
    #pragma unroll
    for (int j = 0; j < 4; ++j) {
        int idx = tid + (j << 6);
        float acc = GW[0] * rowr[idx];
        #pragma unroll
        for (int t = 1; t <= 3; ++t) {
            if (idx - t >= 0)  acc += GW[t] * rowr[idx - t];
            if (idx + t < 256) acc += GW[t] * rowr[idx + t];
        }
        bufA[idx] = make_float2(acc, 0.f);
    }
    __syncthreads();
    fft256(bufA, bufB, TW, tid, -1.f);
    for (int col = tid; col < FREQ_COLS; col += 64) {
        Freq[((size_t)(b * FREQ_COLS + col) << 8) + y] = bufA[col];
    }
}

// K7: column pass — y-blur (complex) + FFT + CTF + inverse FFT
__global__ __launch_bounds__(64) void fft_cols_ctf(float2* __restrict__ Freq,
                                                   const float* __restrict__ ctf) {
    __shared__ float2 bufA[256];
    __shared__ float2 bufB[256];
    __shared__ float2 TW[128];
    int tid = threadIdx.x;
    fill_tw(TW, tid);
    int b = blockIdx.x / FREQ_COLS;
    int col = blockIdx.x - b * FREQ_COLS;
    float2* basep = Freq + ((size_t)(b * FREQ_COLS + col) << 8);
    #pragma unroll
    for (int j = 0; j < 4; ++j) {
        int idx = tid + (j << 6);
        bufB[idx] = basep[idx];
    }
    __syncthreads();
    #pragma unroll
    for (int j = 0; j < 4; ++j) {
        int idx = tid + (j << 6);
        float ax = GW[0] * bufB[idx].x;
        float ay = GW[0] * bufB[idx].y;
        #pragma unroll
        for (int t = 1; t <= 3; ++t) {
            if (idx - t >= 0)  { ax += GW[t] * bufB[idx - t].x; ay += GW[t] * bufB[idx - t].y; }
            if (idx + t < 256) { ax += GW[t] * bufB[idx + t].x; ay += GW[t] * bufB[idx + t].y; }
        }
        bufA[idx] = make_float2(ax, ay);
    }
    __syncthreads();
    fft256(bufA, bufB, TW, tid, -1.f);
    #pragma unroll
    for (int j = 0; j < 4; ++j) {
        int k = tid + (j << 6);
        float c = ctf[(size_t)((b << 8) | k) * FREQ_COLS + col];
        bufA[k].x *= c;
        bufA[k].y *= c;
    }
    __syncthreads();
    fft256(bufA, bufB, TW, tid, +1.f);
    #pragma unroll
    for (int j = 0; j < 4; ++j) {
        int idx = tid + (j << 6);
        basep[idx] = bufA[idx];
    }
}

// K8: Hermitian-extend + inverse row FFT + scale
__global__ __launch_bounds__(64) void fft_rows_inv(const float2* __restrict__ Freq,
                                                   float* __restrict__ out) {
    __shared__ float2 bufA[256];
    __shared__ float2 bufB[256];
    __shared__ float2 TW[128];
    int tid = threadIdx.x;
    fill_tw(TW, tid);
    int b = blockIdx.x >> 8;
    int y = blockIdx.x & 255;
    for (int col = tid; col < FREQ_COLS; col += 64) {
        bufA[col] = Freq[((size_t)(b * FREQ_COLS + col) << 8) + y];
    }
    __syncthreads();
    for (int k = 129 + tid; k < 256; k += 64) {
        float2 v = bufA[256 - k];
        bufA[k] = make_float2(v.x, -v.y);
    }
    __syncthreads();
    fft256(bufA, bufB, TW, tid, +1.f);
    float* row = out + ((size_t)blockIdx.x << 8);
    const float scale = 1.0f / 65536.0f;
    #pragma unroll
    for (int j = 0; j < 4; ++j) {
        int idx = tid + (j << 6);
        row[idx] = bufA[idx].x * scale;
    }
}

// ---------------------------------------------------------------------------
template<int NB>
static void run_binned(const float* coords, const float* values, const float* Wd,
                       const float* bd, float* bdata, unsigned* cnt, unsigned* bases,
                       unsigned* total, unsigned* tileBase, uint2* bucket, float* img,
                       hipStream_t stream) {
    constexpr int T = NB * 16;
    const int NG = BB / NB;
    for (int g = 0; g < NG; ++g) {
        int bstart = g * NB;
        count_kernel<NB><<<NBLK, 256, 0, stream>>>(coords, bdata, cnt, bstart);
        scan_cols_kernel<<<T, 256, 0, stream>>>(cnt, bases, total, T);
        scan_small_kernel<<<1, 256, 0, stream>>>(total, tileBase, T);
        fill_kernel<NB><<<NBLK, 256, 0, stream>>>(coords, values, Wd, bd, bdata,
                                                  bases, tileBase, bucket, bstart);
        accum_kernel<<<T, 1024, 0, stream>>>(bucket, tileBase, total, img, bstart);
    }
}

extern "C" void kernel_launch(void* const* d_in, const int* in_sizes, int n_in,
                              void* d_out, int out_size, void* d_ws, size_t ws_size,
                              hipStream_t stream) {
    const float* rows   = (const float*)d_in[0];
    const float* shifts = (const float*)d_in[1];
    const float* latent = (const float*)d_in[2];
    const float* coords = (const float*)d_in[3];
    const float* values = (const float*)d_in[4];
    const float* W0     = (const float*)d_in[5];
    const float* b0     = (const float*)d_in[6];
    const float* W1     = (const float*)d_in[7];
    const float* b1     = (const float*)d_in[8];
    const float* W2     = (const float*)d_in[9];
    const float* b2     = (const float*)d_in[10];
    const float* W3     = (const float*)d_in[11];
    const float* b3     = (const float*)d_in[12];
    const float* Wd     = (const float*)d_in[13];
    const float* bd     = (const float*)d_in[14];
    const float* ctf    = (const float*)d_in[15];
    float* out = (float*)d_out;

    // Workspace layout
    char* w = (char*)d_ws;
    size_t off = 0;
    float* bdata = (float*)(w + off);  off += 4096;
    float* img   = (float*)(w + off);  off += (size_t)IMG_ELEMS * 4;
    float2* Freq = (float2*)(w + off); off += (size_t)BB * FREQ_COLS * 256 * 8;
    unsigned* cnt   = (unsigned*)(w + off); off += (size_t)NBLK * 256 * 4;
    unsigned* bases = (unsigned*)(w + off); off += (size_t)NBLK * 256 * 4;
    unsigned* total = (unsigned*)(w + off); off += 1024;
    unsigned* tileBase = (unsigned*)(w + off); off += 1024;
    uint2* bucket = (uint2*)(w + off);
    size_t fixed = off;

    int NB = 0;
    if      (ws_size >= fixed + (size_t)NN * 16 * 8) NB = 16;
    else if (ws_size >= fixed + (size_t)NN *  8 * 8) NB = 8;
    else if (ws_size >= fixed + (size_t)NN *  4 * 8) NB = 4;
    else if (ws_size >= fixed + (size_t)NN *  2 * 8) NB = 2;
    else if (ws_size >= fixed + (size_t)NN *  1 * 8) NB = 1;

    prep_kernel<<<1, 64, 0, stream>>>(rows, shifts, latent,
                                      W0, b0, W1, b1, W2, b2, W3, b3, bdata);

    switch (NB) {
    case 16: run_binned<16>(coords, values, Wd, bd, bdata, cnt, bases, total, tileBase, bucket, img, stream); break;
    case 8:  run_binned<8> (coords, values, Wd, bd, bdata, cnt, bases, total, tileBase, bucket, img, stream); break;
    case 4:  run_binned<4> (coords, values, Wd, bd, bdata, cnt, bases, total, tileBase, bucket, img, stream); break;
    case 2:  run_binned<2> (coords, values, Wd, bd, bdata, cnt, bases, total, tileBase, bucket, img, stream); break;
    case 1:  run_binned<1> (coords, values, Wd, bd, bdata, cnt, bases, total, tileBase, bucket, img, stream); break;
    default: {
        int n4 = IMG_ELEMS / 4;
        zero_kernel<<<(n4 + 255) / 256, 256, 0, stream>>>((float4*)img, n4);
        scatter_atomic_kernel<<<NBLK, 256, 0, stream>>>(coords, values, Wd, bd, bdata, img);
    } break;
    }

    fft_rows_fwd<<<BB * XSZ, 64, 0, stream>>>(img, Freq);
    fft_cols_ctf<<<BB * FREQ_COLS, 64, 0, stream>>>(Freq, ctf);
    fft_rows_inv<<<BB * XSZ, 64, 0, stream>>>(Freq, out);
}

// Round 5
// 242.981 us; speedup vs baseline: 2.3442x; 1.0184x over previous
//
#include <hip/hip_runtime.h>
#include <math.h>

// Problem constants (fixed by reference)
#define BB   16
#define LATD 8
#define NN   500000
#define XSZ  256
#define HALF 128
#define IMG_ELEMS (BB * XSZ * XSZ)          // 1,048,576 floats
#define FREQ_COLS 129                        // XS/2+1
#define NBLK ((NN + 255) / 256)              // 1954 point-blocks

// ---------------------------------------------------------------------------
// wave64 inclusive scan (shuffle-based, no barriers)
// ---------------------------------------------------------------------------
__device__ __forceinline__ unsigned wave_incl_scan(unsigned x, int lane) {
    #pragma unroll
    for (int d = 1; d < 64; d <<= 1) {
        unsigned y = __shfl_up(x, d, 64);
        if (lane >= d) x += y;
    }
    return x;
}

// ---------------------------------------------------------------------------
// K0: per-image prep — rotation rows 0/1, shifts+half, SIREN MLP hidden h[8]
// ---------------------------------------------------------------------------
__global__ void prep_kernel(const float* __restrict__ rows,
                            const float* __restrict__ shifts,
                            const float* __restrict__ latent,
                            const float* __restrict__ W0, const float* __restrict__ b0,
                            const float* __restrict__ W1, const float* __restrict__ b1,
                            const float* __restrict__ W2, const float* __restrict__ b2,
                            const float* __restrict__ W3, const float* __restrict__ b3,
                            float* __restrict__ bdata) {
    int b = threadIdx.x;
    if (b >= BB) return;

    float rot  = rows[b * 3 + 0];
    float tilt = rows[b * 3 + 1];
    float psi  = rows[b * 3 + 2];
    float ca, sa, cb, sb, cg, sg;
    sincosf(rot, &sa, &ca);
    sincosf(tilt, &sb, &cb);
    sincosf(psi, &sg, &cg);

    float R00 =  cg * cb * ca - sg * sa;
    float R01 =  cg * cb * sa + sg * ca;
    float R02 = -cg * sb;
    float R10 = -sg * cb * ca - cg * sa;
    float R11 = -sg * cb * sa + cg * ca;
    float R12 =  sg * sb;

    float h[LATD], t[LATD];
    #pragma unroll
    for (int j = 0; j < LATD; ++j) {
        float acc = b0[j];
        #pragma unroll
        for (int l = 0; l < LATD; ++l) acc += latent[b * LATD + l] * W0[l * LATD + j];
        t[j] = acc;
    }
    #pragma unroll
    for (int j = 0; j < LATD; ++j) h[j] = sinf(30.0f * t[j]);

    const float* Ws[3] = {W1, W2, W3};
    const float* bs[3] = {b1, b2, b3};
    for (int L = 0; L < 3; ++L) {
        #pragma unroll
        for (int j = 0; j < LATD; ++j) {
            float acc = bs[L][j];
            #pragma unroll
            for (int l = 0; l < LATD; ++l) acc += h[l] * Ws[L][l * LATD + j];
            t[j] = acc;
        }
        #pragma unroll
        for (int j = 0; j < LATD; ++j) h[j] += sinf(t[j]);
    }

    float* P = bdata + b * 16;
    P[0] = R00; P[1] = R01; P[2] = R02;
    P[3] = R10; P[4] = R11; P[5] = R12;
    P[6] = shifts[b * 2 + 0] + (float)HALF;
    P[7] = shifts[b * 2 + 1] + (float)HALF;
    #pragma unroll
    for (int j = 0; j < LATD; ++j) P[8 + j] = h[j];
}

// Shared projection helper — MUST be bit-identical between count and fill.
__device__ __forceinline__ int2 project_px(const float* __restrict__ Q,
                                           float cx, float cy, float cz) {
    float x = fmaf(Q[0], cx, fmaf(Q[1], cy, fmaf(Q[2], cz, Q[6])));
    float y = fmaf(Q[3], cx, fmaf(Q[4], cy, fmaf(Q[5], cz, Q[7])));
    float px = fminf(fmaxf(rintf(x), 0.f), 255.f);
    float py = fminf(fmaxf(rintf(y), 0.f), 255.f);
    return make_int2((int)px, (int)py);
}

// ---------------------------------------------------------------------------
// K1: count — per-(block,tile) histogram. Tile = (image, 16-row band).
// ---------------------------------------------------------------------------
template<int NB>
__global__ __launch_bounds__(256) void count_kernel(
        const float* __restrict__ coords, const float* __restrict__ bdata,
        unsigned* __restrict__ cnt, int bstart) {
    constexpr int T = NB * 16;
    __shared__ float    P[NB * 16];
    __shared__ unsigned hist[T];
    int tid = threadIdx.x;
    if (tid < NB * 16) P[tid] = bdata[bstart * 16 + tid];
    if (tid < T) hist[tid] = 0;
    __syncthreads();

    int n = blockIdx.x * 256 + tid;
    if (n < NN) {
        float cx = coords[n * 3 + 0];
        float cy = coords[n * 3 + 1];
        float cz = coords[n * 3 + 2];
        #pragma unroll
        for (int bi = 0; bi < NB; ++bi) {
            int2 p = project_px(&P[bi * 16], cx, cy, cz);
            int tile = bi * 16 + (p.y >> 4);
            atomicAdd(&hist[tile], 1u);
        }
    }
    __syncthreads();
    if (tid < T) cnt[(size_t)blockIdx.x * T + tid] = hist[tid];
}

// ---------------------------------------------------------------------------
// K2: column scan — bases[blk][t] = sum_{blk'<blk} cnt[blk'][t]; total[t].
// ---------------------------------------------------------------------------
__global__ __launch_bounds__(256) void scan_cols_kernel(
        const unsigned* __restrict__ cnt, unsigned* __restrict__ bases,
        unsigned* __restrict__ total, int T) {
    __shared__ unsigned wsum[2][4];
    int t = blockIdx.x;
    int tid = threadIdx.x;
    int lane = tid & 63;
    int wv = tid >> 6;
    unsigned running = 0;
    const int nchunk = (NBLK + 255) >> 8;
    for (int c = 0; c < nchunk; ++c) {
        int blk = (c << 8) + tid;
        unsigned v = (blk < NBLK) ? cnt[(size_t)blk * T + t] : 0u;
        unsigned s = wave_incl_scan(v, lane);
        if (lane == 63) wsum[c & 1][wv] = s;
        __syncthreads();
        unsigned off = 0, tot = 0;
        #pragma unroll
        for (int i = 0; i < 4; ++i) {
            unsigned u = wsum[c & 1][i];
            if (i < wv) off += u;
            tot += u;
        }
        if (blk < NBLK) bases[(size_t)blk * T + t] = running + s + off - v;
        running += tot;
    }
    if (tid == 0) total[t] = running;
}

// K3: exclusive scan of tile totals -> tileBase. Single block, shuffle scan.
__global__ __launch_bounds__(256) void scan_small_kernel(
        const unsigned* __restrict__ total, unsigned* __restrict__ tileBase, int T) {
    __shared__ unsigned wsum[4];
    int tid = threadIdx.x;
    int lane = tid & 63;
    int wv = tid >> 6;
    unsigned v = (tid < T) ? total[tid] : 0u;
    unsigned s = wave_incl_scan(v, lane);
    if (lane == 63) wsum[wv] = s;
    __syncthreads();
    unsigned off = 0;
    #pragma unroll
    for (int i = 0; i < 4; ++i) { unsigned u = wsum[i]; if (i < wv) off += u; }
    if (tid < T) tileBase[tid] = s + off - v;
}

// ---------------------------------------------------------------------------
// K4: fill — recompute projection + delta, rank via LDS fetch_add, stage
// tile-ordered in LDS, write coalesced {off12, value} records to buckets.
// ---------------------------------------------------------------------------
template<int NB>
__global__ __launch_bounds__(256) void fill_kernel(
        const float* __restrict__ coords, const float* __restrict__ values,
        const float* __restrict__ Wd, const float* __restrict__ bd,
        const float* __restrict__ bdata, const unsigned* __restrict__ bases,
        const unsigned* __restrict__ tileBase, uint2* __restrict__ bucket,
        int bstart) {
    constexpr int T = NB * 16;
    __shared__ float    P[NB * 16];
    __shared__ unsigned hist[T];
    __shared__ unsigned wsum[4];
    __shared__ unsigned lbase[T];
    __shared__ unsigned gadj[T];
    __shared__ uint2    stage[256 * NB];

    int tid = threadIdx.x;
    int blk = blockIdx.x;
    int lane = tid & 63;
    int wv = tid >> 6;
    if (tid < NB * 16) P[tid] = bdata[bstart * 16 + tid];
    if (tid < T) hist[tid] = 0;
    __syncthreads();

    int n = blk * 256 + tid;
    bool active = (n < NN);

    unsigned word[NB];
    unsigned rank[NB];
    float    fval[NB];
    if (active) {
        float cx = coords[n * 3 + 0];
        float cy = coords[n * 3 + 1];
        float cz = coords[n * 3 + 2];
        float base = values[n] + bd[n];
        float wd[LATD];
        #pragma unroll
        for (int l = 0; l < LATD; ++l) wd[l] = Wd[l * NN + n];
        #pragma unroll
        for (int bi = 0; bi < NB; ++bi) {
            const float* Q = &P[bi * 16];
            int2 p = project_px(Q, cx, cy, cz);
            float delta = 0.f;
            #pragma unroll
            for (int l = 0; l < LATD; ++l) delta = fmaf(Q[8 + l], wd[l], delta);
            int tile = bi * 16 + (p.y >> 4);
            int off12 = ((p.y & 15) << 8) | p.x;
            word[bi] = (unsigned)(off12 | (tile << 12));
            fval[bi] = base + delta;
            rank[bi] = atomicAdd(&hist[tile], 1u);
        }
    }
    __syncthreads();

    unsigned v = (tid < T) ? hist[tid] : 0u;
    unsigned s = wave_incl_scan(v, lane);
    if (lane == 63) wsum[wv] = s;
    __syncthreads();
    unsigned off = 0;
    #pragma unroll
    for (int i = 0; i < 4; ++i) { unsigned u = wsum[i]; if (i < wv) off += u; }
    unsigned excl = s + off - v;
    if (tid < T) {
        lbase[tid] = excl;
        gadj[tid]  = tileBase[tid] + bases[(size_t)blk * T + tid] - excl;
    }
    __syncthreads();

    if (active) {
        #pragma unroll
        for (int bi = 0; bi < NB; ++bi) {
            unsigned t = word[bi] >> 12;
            stage[lbase[t] + rank[bi]] = make_uint2(word[bi], __float_as_uint(fval[bi]));
        }
    }
    __syncthreads();

    int nactive = NN - blk * 256;
    if (nactive > 256) nactive = 256;
    int tot = nactive * NB;
    for (int i = tid; i < tot; i += 256) {
        uint2 e = stage[i];
        unsigned t = e.x >> 12;
        bucket[gadj[t] + i] = make_uint2(e.x & 0xFFFu, e.y);
    }
}

// ---------------------------------------------------------------------------
// K5: accum — one 1024-thread block per tile. 4 LDS replicas of the tile with
// an XOR bank-swizzle: replica r = tid&3, address = r*4096 + (pix ^ (r<<3)).
// Same hot pixel -> 4 distinct addresses in 4 distinct banks, cutting LDS
// same-address / same-bank atomic serialization ~4x. Merge at writeout.
// ---------------------------------------------------------------------------
__global__ __launch_bounds__(1024) void accum_kernel(
        const uint2* __restrict__ bucket, const unsigned* __restrict__ tileBase,
        const unsigned* __restrict__ total, float* __restrict__ img, int bstart) {
    __shared__ float rep[4 * 4096];
    int t = blockIdx.x;
    int tid = threadIdx.x;
    for (int i = tid; i < 4 * 4096; i += 1024) rep[i] = 0.f;
    __syncthreads();
    unsigned s0 = tileBase[t];
    unsigned cntt = total[t];
    unsigned rbase = (unsigned)(tid & 3) << 12;
    unsigned rxor  = (unsigned)(tid & 3) << 3;
    unsigned nchunk = (cntt + 4095) >> 12;
    for (unsigned c = 0; c < nchunk; ++c) {
        unsigned base = s0 + (c << 12);
        unsigned rem  = cntt - (c << 12);
        uint2 e[4];
        unsigned idx[4];
        #pragma unroll
        for (int k = 0; k < 4; ++k) {
            idx[k] = (unsigned)(k << 10) + tid;
            if (idx[k] < rem) e[k] = bucket[base + idx[k]];
        }
        #pragma unroll
        for (int k = 0; k < 4; ++k) {
            if (idx[k] < rem) {
                unsigned pix = e[k].x & 4095u;
                atomicAdd(&rep[rbase + (pix ^ rxor)], __uint_as_float(e[k].y));
            }
        }
    }
    __syncthreads();
    int b = bstart + (t >> 4);
    int band = t & 15;
    float* dst = img + ((size_t)b << 16) + (band << 12);
    for (int i = tid; i < 4096; i += 1024) {
        float s = rep[i] + rep[4096 + (i ^ 8)] + rep[8192 + (i ^ 16)] + rep[12288 + (i ^ 24)];
        dst[i] = s;
    }
}

// ---------------------------------------------------------------------------
// Fallback: device-scope atomic scatter (R1 path) + zero
// ---------------------------------------------------------------------------
__global__ void zero_kernel(float4* __restrict__ p, int n4) {
    int i = blockIdx.x * blockDim.x + threadIdx.x;
    if (i < n4) p[i] = make_float4(0.f, 0.f, 0.f, 0.f);
}

__global__ __launch_bounds__(256) void scatter_atomic_kernel(
        const float* __restrict__ coords, const float* __restrict__ values,
        const float* __restrict__ Wd, const float* __restrict__ bd,
        const float* __restrict__ bdata, float* __restrict__ img) {
    __shared__ float P[BB * 16];
    P[threadIdx.x] = bdata[threadIdx.x];
    __syncthreads();
    int n = blockIdx.x * 256 + threadIdx.x;
    if (n >= NN) return;
    float cx = coords[n * 3 + 0];
    float cy = coords[n * 3 + 1];
    float cz = coords[n * 3 + 2];
    float base = values[n] + bd[n];
    float wd[LATD];
    #pragma unroll
    for (int l = 0; l < LATD; ++l) wd[l] = Wd[l * NN + n];
    #pragma unroll
    for (int b = 0; b < BB; ++b) {
        const float* Q = &P[b * 16];
        int2 p = project_px(Q, cx, cy, cz);
        float delta = 0.f;
        #pragma unroll
        for (int l = 0; l < LATD; ++l) delta = fmaf(Q[8 + l], wd[l], delta);
        atomicAdd(img + ((b << 16) | (p.y << 8) | p.x), base + delta);
    }
}

// ---------------------------------------------------------------------------
// Gaussian 7-tap weights (sigma=1, radius=3, normalized)
// ---------------------------------------------------------------------------
__device__ __constant__ float GW[4] = {0.39905027f, 0.24203623f, 0.05400558f, 0.00443305f};

// ---------------------------------------------------------------------------
// 256-point complex Stockham FFT in LDS, one 64-lane slice per FFT.
// TW[m] = (cos,sin) of 2*pi*m/256; dir=-1 fwd, +1 inv (unnormalized).
// Barriers are block-wide: all slices run the same stage count in lockstep.
// ---------------------------------------------------------------------------
__device__ __forceinline__ void fft256(float2* src, float2* dst,
                                       const float2* __restrict__ TW,
                                       int lane, float dir) {
    #pragma unroll
    for (int t = 0; t < 8; ++t) {
        const int s = 1 << t;
        #pragma unroll
        for (int r = 0; r < 2; ++r) {
            int i = lane + (r << 6);
            int q = i & (s - 1);
            int p = i >> t;
            float2 a = src[q + s * p];
            float2 b = src[q + s * p + 128];
            int m = p << t;
            float cs = TW[m].x;
            float sn = dir * TW[m].y;
            float2 sum = make_float2(a.x + b.x, a.y + b.y);
            float dx = a.x - b.x;
            float dy = a.y - b.y;
            float2 tw = make_float2(dx * cs - dy * sn, dx * sn + dy * cs);
            int o = q + ((p * s) << 1);
            dst[o] = sum;
            dst[o + s] = tw;
        }
        __syncthreads();
        float2* tmp = src; src = dst; dst = tmp;
    }
}

__device__ __forceinline__ void fill_tw256(float2* TW, int tid) {
    if (tid < 128) {
        float sn, cs;
        sincosf(0.0245436926061703f * (float)tid, &sn, &cs);
        TW[tid] = make_float2(cs, sn);
    }
}

// ---------------------------------------------------------------------------
// K6: x-blur + forward row rFFT, 4 rows per 256-thread block.
// Transposed store Freq[b][col][y] hits 32B-contiguous groups (y0..y0+3).
// ---------------------------------------------------------------------------
__global__ __launch_bounds__(256) void fft_rows_fwd(const float* __restrict__ img,
                                                    float2* __restrict__ Freq) {
    __shared__ float2 bufA[4][256];
    __shared__ float2 bufB[4][256];
    __shared__ float2 TW[128];
    __shared__ float  rowr[4][256];
    int tid = threadIdx.x;
    int lane = tid & 63;
    int sub = tid >> 6;
    fill_tw256(TW, tid);
    int b  = blockIdx.x >> 6;
    int y0 = (blockIdx.x & 63) << 2;

    const float* src = img + (((size_t)(b << 8) + y0) << 8);
    for (int i = tid; i < 1024; i += 256) ((float*)rowr)[i] = src[i];
    __syncthreads();

    #pragma unroll
    for (int j = 0; j < 4; ++j) {
        int x = lane + (j << 6);
        float acc = GW[0] * rowr[sub][x];
        #pragma unroll
        for (int t = 1; t <= 3; ++t) {
            if (x - t >= 0)  acc += GW[t] * rowr[sub][x - t];
            if (x + t < 256) acc += GW[t] * rowr[sub][x + t];
        }
        bufA[sub][x] = make_float2(acc, 0.f);
    }
    __syncthreads();
    fft256(bufA[sub], bufB[sub], TW, lane, -1.f);

    // store: consecutive tid -> consecutive y within col (32B groups)
    for (int i = tid; i < FREQ_COLS * 4; i += 256) {
        int col = i >> 2;
        int s   = i & 3;
        Freq[((size_t)(b * FREQ_COLS + col) << 8) + y0 + s] = bufA[s][col];
    }
}

// ---------------------------------------------------------------------------
// K7: column pass — y-blur (complex) + FFT + CTF + inverse FFT, 4 cols/block.
// ---------------------------------------------------------------------------
__global__ __launch_bounds__(256) void fft_cols_ctf(float2* __restrict__ Freq,
                                                    const float* __restrict__ ctf) {
    __shared__ float2 bufA[4][256];
    __shared__ float2 bufB[4][256];
    __shared__ float2 TW[128];
    int tid = threadIdx.x;
    int lane = tid & 63;
    int sub = tid >> 6;
    fill_tw256(TW, tid);
    int b  = blockIdx.x / 33;
    int c0 = (blockIdx.x - b * 33) << 2;
    int col  = c0 + sub;
    int colc = col < FREQ_COLS ? col : (FREQ_COLS - 1);
    float2* basep = Freq + ((size_t)(b * FREQ_COLS + colc) << 8);

    #pragma unroll
    for (int j = 0; j < 4; ++j) {
        int k = lane + (j << 6);
        bufB[sub][k] = basep[k];
    }
    __syncthreads();
    // y-blur (zero-padded SAME), complex
    #pragma unroll
    for (int j = 0; j < 4; ++j) {
        int k = lane + (j << 6);
        float ax = GW[0] * bufB[sub][k].x;
        float ay = GW[0] * bufB[sub][k].y;
        #pragma unroll
        for (int t = 1; t <= 3; ++t) {
            if (k - t >= 0)  { ax += GW[t] * bufB[sub][k - t].x; ay += GW[t] * bufB[sub][k - t].y; }
            if (k + t < 256) { ax += GW[t] * bufB[sub][k + t].x; ay += GW[t] * bufB[sub][k + t].y; }
        }
        bufA[sub][k] = make_float2(ax, ay);
    }
    __syncthreads();
    fft256(bufA[sub], bufB[sub], TW, lane, -1.f);
    #pragma unroll
    for (int j = 0; j < 4; ++j) {
        int k = lane + (j << 6);
        float c = ctf[(size_t)((b << 8) | k) * FREQ_COLS + colc];
        bufA[sub][k].x *= c;
        bufA[sub][k].y *= c;
    }
    __syncthreads();
    fft256(bufA[sub], bufB[sub], TW, lane, +1.f);
    if (col < FREQ_COLS) {
        #pragma unroll
        for (int j = 0; j < 4; ++j) {
            int k = lane + (j << 6);
            basep[k] = bufA[sub][k];
        }
    }
}

// ---------------------------------------------------------------------------
// K8: Hermitian-extend + inverse row FFT + scale, 4 rows per block.
// ---------------------------------------------------------------------------
__global__ __launch_bounds__(256) void fft_rows_inv(const float2* __restrict__ Freq,
                                                    float* __restrict__ out) {
    __shared__ float2 bufA[4][256];
    __shared__ float2 bufB[4][256];
    __shared__ float2 TW[128];
    int tid = threadIdx.x;
    int lane = tid & 63;
    int sub = tid >> 6;
    fill_tw256(TW, tid);
    int b  = blockIdx.x >> 6;
    int y0 = (blockIdx.x & 63) << 2;

    for (int i = tid; i < FREQ_COLS * 4; i += 256) {
        int col = i >> 2;
        int s   = i & 3;
        bufA[s][col] = Freq[((size_t)(b * FREQ_COLS + col) << 8) + y0 + s];
    }
    __syncthreads();
    for (int k = FREQ_COLS + lane; k < 256; k += 64) {
        float2 v = bufA[sub][256 - k];
        bufA[sub][k] = make_float2(v.x, -v.y);
    }
    __syncthreads();
    fft256(bufA[sub], bufB[sub], TW, lane, +1.f);
    float* dst = out + (((size_t)(b << 8) + y0) << 8);
    const float scale = 1.0f / 65536.0f;
    for (int i = tid; i < 1024; i += 256) {
        dst[i] = bufA[i >> 8][i & 255].x * scale;
    }
}

// ---------------------------------------------------------------------------
template<int NB>
static void run_binned(const float* coords, const float* values, const float* Wd,
                       const float* bd, float* bdata, unsigned* cnt, unsigned* bases,
                       unsigned* total, unsigned* tileBase, uint2* bucket, float* img,
                       hipStream_t stream) {
    constexpr int T = NB * 16;
    const int NG = BB / NB;
    for (int g = 0; g < NG; ++g) {
        int bstart = g * NB;
        count_kernel<NB><<<NBLK, 256, 0, stream>>>(coords, bdata, cnt, bstart);
        scan_cols_kernel<<<T, 256, 0, stream>>>(cnt, bases, total, T);
        scan_small_kernel<<<1, 256, 0, stream>>>(total, tileBase, T);
        fill_kernel<NB><<<NBLK, 256, 0, stream>>>(coords, values, Wd, bd, bdata,
                                                  bases, tileBase, bucket, bstart);
        accum_kernel<<<T, 1024, 0, stream>>>(bucket, tileBase, total, img, bstart);
    }
}

extern "C" void kernel_launch(void* const* d_in, const int* in_sizes, int n_in,
                              void* d_out, int out_size, void* d_ws, size_t ws_size,
                              hipStream_t stream) {
    const float* rows   = (const float*)d_in[0];
    const float* shifts = (const float*)d_in[1];
    const float* latent = (const float*)d_in[2];
    const float* coords = (const float*)d_in[3];
    const float* values = (const float*)d_in[4];
    const float* W0     = (const float*)d_in[5];
    const float* b0     = (const float*)d_in[6];
    const float* W1     = (const float*)d_in[7];
    const float* b1     = (const float*)d_in[8];
    const float* W2     = (const float*)d_in[9];
    const float* b2     = (const float*)d_in[10];
    const float* W3     = (const float*)d_in[11];
    const float* b3     = (const float*)d_in[12];
    const float* Wd     = (const float*)d_in[13];
    const float* bd     = (const float*)d_in[14];
    const float* ctf    = (const float*)d_in[15];
    float* out = (float*)d_out;

    // Workspace layout (identical to R4 — proven fit)
    char* w = (char*)d_ws;
    size_t off = 0;
    float* bdata = (float*)(w + off);  off += 4096;
    float* img   = (float*)(w + off);  off += (size_t)IMG_ELEMS * 4;
    float2* Freq = (float2*)(w + off); off += (size_t)BB * FREQ_COLS * 256 * 8;
    unsigned* cnt   = (unsigned*)(w + off); off += (size_t)NBLK * 256 * 4;
    unsigned* bases = (unsigned*)(w + off); off += (size_t)NBLK * 256 * 4;
    unsigned* total = (unsigned*)(w + off); off += 1024;
    unsigned* tileBase = (unsigned*)(w + off); off += 1024;
    uint2* bucket = (uint2*)(w + off);
    size_t fixed = off;

    int NB = 0;
    if      (ws_size >= fixed + (size_t)NN * 16 * 8) NB = 16;
    else if (ws_size >= fixed + (size_t)NN *  8 * 8) NB = 8;
    else if (ws_size >= fixed + (size_t)NN *  4 * 8) NB = 4;
    else if (ws_size >= fixed + (size_t)NN *  2 * 8) NB = 2;
    else if (ws_size >= fixed + (size_t)NN *  1 * 8) NB = 1;

    prep_kernel<<<1, 64, 0, stream>>>(rows, shifts, latent,
                                      W0, b0, W1, b1, W2, b2, W3, b3, bdata);

    switch (NB) {
    case 16: run_binned<16>(coords, values, Wd, bd, bdata, cnt, bases, total, tileBase, bucket, img, stream); break;
    case 8:  run_binned<8> (coords, values, Wd, bd, bdata, cnt, bases, total, tileBase, bucket, img, stream); break;
    case 4:  run_binned<4> (coords, values, Wd, bd, bdata, cnt, bases, total, tileBase, bucket, img, stream); break;
    case 2:  run_binned<2> (coords, values, Wd, bd, bdata, cnt, bases, total, tileBase, bucket, img, stream); break;
    case 1:  run_binned<1> (coords, values, Wd, bd, bdata, cnt, bases, total, tileBase, bucket, img, stream); break;
    default: {
        int n4 = IMG_ELEMS / 4;
        zero_kernel<<<(n4 + 255) / 256, 256, 0, stream>>>((float4*)img, n4);
        scatter_atomic_kernel<<<NBLK, 256, 0, stream>>>(coords, values, Wd, bd, bdata, img);
    } break;
    }

    fft_rows_fwd<<<BB * 64, 256, 0, stream>>>(img, Freq);
    fft_cols_ctf<<<BB * 33, 256, 0, stream>>>(Freq, ctf);
    fft_rows_inv<<<BB * 64, 256, 0, stream>>>(Freq, out);
}

// Round 6
// 242.334 us; speedup vs baseline: 2.3504x; 1.0027x over previous
//
#include <hip/hip_runtime.h>
#include <math.h>

// Problem constants (fixed by reference)
#define BB   16
#define LATD 8
#define NN   500000
#define XSZ  256
#define HALF 128
#define IMG_ELEMS (BB * XSZ * XSZ)          // 1,048,576 floats
#define FREQ_COLS 129                        // XS/2+1
#define NBLK ((NN + 255) / 256)              // 1954 point-blocks

// Entry packing: bits[11:0] = pixel-in-tile, bits[31:12] = top 20 bits of the
// fp32 value (round-to-nearest on the dropped 12 mantissa bits).
__device__ __forceinline__ unsigned pack_entry(float v, int off12) {
    unsigned pv = (__float_as_uint(v) + 0x800u) & 0xFFFFF000u;
    return pv | (unsigned)off12;
}
__device__ __forceinline__ float entry_val(unsigned e) {
    return __uint_as_float(e & 0xFFFFF000u);
}

// ---------------------------------------------------------------------------
// wave64 inclusive scan (shuffle-based, no barriers)
// ---------------------------------------------------------------------------
__device__ __forceinline__ unsigned wave_incl_scan(unsigned x, int lane) {
    #pragma unroll
    for (int d = 1; d < 64; d <<= 1) {
        unsigned y = __shfl_up(x, d, 64);
        if (lane >= d) x += y;
    }
    return x;
}

// ---------------------------------------------------------------------------
// K0: per-image prep — rotation rows 0/1, shifts+half, SIREN MLP hidden h[8]
// ---------------------------------------------------------------------------
__global__ void prep_kernel(const float* __restrict__ rows,
                            const float* __restrict__ shifts,
                            const float* __restrict__ latent,
                            const float* __restrict__ W0, const float* __restrict__ b0,
                            const float* __restrict__ W1, const float* __restrict__ b1,
                            const float* __restrict__ W2, const float* __restrict__ b2,
                            const float* __restrict__ W3, const float* __restrict__ b3,
                            float* __restrict__ bdata) {
    int b = threadIdx.x;
    if (b >= BB) return;

    float rot  = rows[b * 3 + 0];
    float tilt = rows[b * 3 + 1];
    float psi  = rows[b * 3 + 2];
    float ca, sa, cb, sb, cg, sg;
    sincosf(rot, &sa, &ca);
    sincosf(tilt, &sb, &cb);
    sincosf(psi, &sg, &cg);

    float R00 =  cg * cb * ca - sg * sa;
    float R01 =  cg * cb * sa + sg * ca;
    float R02 = -cg * sb;
    float R10 = -sg * cb * ca - cg * sa;
    float R11 = -sg * cb * sa + cg * ca;
    float R12 =  sg * sb;

    float h[LATD], t[LATD];
    #pragma unroll
    for (int j = 0; j < LATD; ++j) {
        float acc = b0[j];
        #pragma unroll
        for (int l = 0; l < LATD; ++l) acc += latent[b * LATD + l] * W0[l * LATD + j];
        t[j] = acc;
    }
    #pragma unroll
    for (int j = 0; j < LATD; ++j) h[j] = sinf(30.0f * t[j]);

    const float* Ws[3] = {W1, W2, W3};
    const float* bs[3] = {b1, b2, b3};
    for (int L = 0; L < 3; ++L) {
        #pragma unroll
        for (int j = 0; j < LATD; ++j) {
            float acc = bs[L][j];
            #pragma unroll
            for (int l = 0; l < LATD; ++l) acc += h[l] * Ws[L][l * LATD + j];
            t[j] = acc;
        }
        #pragma unroll
        for (int j = 0; j < LATD; ++j) h[j] += sinf(t[j]);
    }

    float* P = bdata + b * 16;
    P[0] = R00; P[1] = R01; P[2] = R02;
    P[3] = R10; P[4] = R11; P[5] = R12;
    P[6] = shifts[b * 2 + 0] + (float)HALF;
    P[7] = shifts[b * 2 + 1] + (float)HALF;
    #pragma unroll
    for (int j = 0; j < LATD; ++j) P[8 + j] = h[j];
}

// Shared projection helper — MUST be bit-identical between count and fill.
__device__ __forceinline__ int2 project_px(const float* __restrict__ Q,
                                           float cx, float cy, float cz) {
    float x = fmaf(Q[0], cx, fmaf(Q[1], cy, fmaf(Q[2], cz, Q[6])));
    float y = fmaf(Q[3], cx, fmaf(Q[4], cy, fmaf(Q[5], cz, Q[7])));
    float px = fminf(fmaxf(rintf(x), 0.f), 255.f);
    float py = fminf(fmaxf(rintf(y), 0.f), 255.f);
    return make_int2((int)px, (int)py);
}
// y-only variant for count — identical fmaf/rint/clamp sequence for y.
__device__ __forceinline__ int project_band(const float* __restrict__ Q,
                                            float cx, float cy, float cz) {
    float y = fmaf(Q[3], cx, fmaf(Q[4], cy, fmaf(Q[5], cz, Q[7])));
    float py = fminf(fmaxf(rintf(y), 0.f), 255.f);
    return ((int)py) >> 4;
}

// ---------------------------------------------------------------------------
// K1: count — per-(block,tile) histogram. Tile = (image, 16-row band).
// Only the y-projection is needed for the tile id.
// ---------------------------------------------------------------------------
template<int NB>
__global__ __launch_bounds__(256) void count_kernel(
        const float* __restrict__ coords, const float* __restrict__ bdata,
        unsigned* __restrict__ cnt, int bstart) {
    constexpr int T = NB * 16;
    __shared__ float    P[NB * 16];
    __shared__ unsigned hist[T];
    int tid = threadIdx.x;
    if (tid < NB * 16) P[tid] = bdata[bstart * 16 + tid];
    if (tid < T) hist[tid] = 0;
    __syncthreads();

    int n = blockIdx.x * 256 + tid;
    if (n < NN) {
        float cx = coords[n * 3 + 0];
        float cy = coords[n * 3 + 1];
        float cz = coords[n * 3 + 2];
        #pragma unroll
        for (int bi = 0; bi < NB; ++bi) {
            int band = project_band(&P[bi * 16], cx, cy, cz);
            atomicAdd(&hist[bi * 16 + band], 1u);
        }
    }
    __syncthreads();
    if (tid < T) cnt[(size_t)blockIdx.x * T + tid] = hist[tid];
}

// ---------------------------------------------------------------------------
// K2: column scan — bases[blk][t] = sum_{blk'<blk} cnt[blk'][t]; total[t].
// ---------------------------------------------------------------------------
__global__ __launch_bounds__(256) void scan_cols_kernel(
        const unsigned* __restrict__ cnt, unsigned* __restrict__ bases,
        unsigned* __restrict__ total, int T) {
    __shared__ unsigned wsum[2][4];
    int t = blockIdx.x;
    int tid = threadIdx.x;
    int lane = tid & 63;
    int wv = tid >> 6;
    unsigned running = 0;
    const int nchunk = (NBLK + 255) >> 8;
    for (int c = 0; c < nchunk; ++c) {
        int blk = (c << 8) + tid;
        unsigned v = (blk < NBLK) ? cnt[(size_t)blk * T + t] : 0u;
        unsigned s = wave_incl_scan(v, lane);
        if (lane == 63) wsum[c & 1][wv] = s;
        __syncthreads();
        unsigned off = 0, tot = 0;
        #pragma unroll
        for (int i = 0; i < 4; ++i) {
            unsigned u = wsum[c & 1][i];
            if (i < wv) off += u;
            tot += u;
        }
        if (blk < NBLK) bases[(size_t)blk * T + t] = running + s + off - v;
        running += tot;
    }
    if (tid == 0) total[t] = running;
}

// K3: exclusive scan of tile totals -> tileBase. Single block, shuffle scan.
__global__ __launch_bounds__(256) void scan_small_kernel(
        const unsigned* __restrict__ total, unsigned* __restrict__ tileBase, int T) {
    __shared__ unsigned wsum[4];
    int tid = threadIdx.x;
    int lane = tid & 63;
    int wv = tid >> 6;
    unsigned v = (tid < T) ? total[tid] : 0u;
    unsigned s = wave_incl_scan(v, lane);
    if (lane == 63) wsum[wv] = s;
    __syncthreads();
    unsigned off = 0;
    #pragma unroll
    for (int i = 0; i < 4; ++i) { unsigned u = wsum[i]; if (i < wv) off += u; }
    if (tid < T) tileBase[tid] = s + off - v;
}

// ---------------------------------------------------------------------------
// K4: fill — projection + delta, rank via LDS fetch_add, stage tile-ordered
// packed 4-byte entries in LDS, coalesced writes to bucket segments.
// ---------------------------------------------------------------------------
template<int NB>
__global__ __launch_bounds__(256) void fill_kernel(
        const float* __restrict__ coords, const float* __restrict__ values,
        const float* __restrict__ Wd, const float* __restrict__ bd,
        const float* __restrict__ bdata, const unsigned* __restrict__ bases,
        const unsigned* __restrict__ tileBase, unsigned* __restrict__ bucket,
        int bstart) {
    constexpr int T = NB * 16;
    __shared__ float    P[NB * 16];
    __shared__ unsigned hist[T];
    __shared__ unsigned wsum[4];
    __shared__ unsigned lbase[T];
    __shared__ unsigned gadj[T];
    __shared__ unsigned stage[256 * NB];
    __shared__ unsigned char tileOf[256 * NB];

    int tid = threadIdx.x;
    int blk = blockIdx.x;
    int lane = tid & 63;
    int wv = tid >> 6;
    if (tid < NB * 16) P[tid] = bdata[bstart * 16 + tid];
    if (tid < T) hist[tid] = 0;
    __syncthreads();

    int n = blk * 256 + tid;
    bool active = (n < NN);

    unsigned word[NB];
    unsigned rank[NB];
    unsigned char tl[NB];
    if (active) {
        float cx = coords[n * 3 + 0];
        float cy = coords[n * 3 + 1];
        float cz = coords[n * 3 + 2];
        float base = values[n] + bd[n];
        float wd[LATD];
        #pragma unroll
        for (int l = 0; l < LATD; ++l) wd[l] = Wd[l * NN + n];
        #pragma unroll
        for (int bi = 0; bi < NB; ++bi) {
            const float* Q = &P[bi * 16];
            int2 p = project_px(Q, cx, cy, cz);
            float delta = 0.f;
            #pragma unroll
            for (int l = 0; l < LATD; ++l) delta = fmaf(Q[8 + l], wd[l], delta);
            int tile = bi * 16 + (p.y >> 4);
            int off12 = ((p.y & 15) << 8) | p.x;
            word[bi] = pack_entry(base + delta, off12);
            tl[bi] = (unsigned char)tile;
            rank[bi] = atomicAdd(&hist[tile], 1u);
        }
    }
    __syncthreads();

    unsigned v = (tid < T) ? hist[tid] : 0u;
    unsigned s = wave_incl_scan(v, lane);
    if (lane == 63) wsum[wv] = s;
    __syncthreads();
    unsigned off = 0;
    #pragma unroll
    for (int i = 0; i < 4; ++i) { unsigned u = wsum[i]; if (i < wv) off += u; }
    unsigned excl = s + off - v;
    if (tid < T) {
        lbase[tid] = excl;
        gadj[tid]  = tileBase[tid] + bases[(size_t)blk * T + tid] - excl;
    }
    __syncthreads();

    if (active) {
        #pragma unroll
        for (int bi = 0; bi < NB; ++bi) {
            unsigned slot = lbase[tl[bi]] + rank[bi];
            stage[slot] = word[bi];
            tileOf[slot] = tl[bi];
        }
    }
    __syncthreads();

    int nactive = NN - blk * 256;
    if (nactive > 256) nactive = 256;
    int tot = nactive * NB;
    for (int i = tid; i < tot; i += 256) {
        unsigned t = tileOf[i];
        bucket[gadj[t] + i] = stage[i];
    }
}

// ---------------------------------------------------------------------------
// K5a: accum_split — M blocks per tile. Block (t,m) accumulates an equal
// slice of tile t's bucket segment into a private LDS tile, then writes the
// PARTIAL tile to partials[m][t]. No zeroing, no global atomics; the partial
// sum happens in fft_rows_fwd's load (linearity). Kills the straggler-tile
// serialization that pinned accum at 68us across R3-R5.
// ---------------------------------------------------------------------------
__global__ __launch_bounds__(512) void accum_split_kernel(
        const unsigned* __restrict__ bucket, const unsigned* __restrict__ tileBase,
        const unsigned* __restrict__ total, float* __restrict__ partials,
        int T, int M) {
    __shared__ float tile[4096];
    int t = blockIdx.x % T;
    int m = blockIdx.x / T;
    int tid = threadIdx.x;
    for (int i = tid; i < 4096; i += 512) tile[i] = 0.f;
    __syncthreads();
    unsigned s0 = tileBase[t];
    unsigned c  = total[t];
    unsigned e0 = s0 + (unsigned)(((unsigned long long)c * (unsigned)m) / (unsigned)M);
    unsigned e1 = s0 + (unsigned)(((unsigned long long)c * (unsigned)(m + 1)) / (unsigned)M);
    unsigned cnt2 = e1 - e0;
    for (unsigned i0 = 0; i0 < cnt2; i0 += 2048) {
        unsigned e[4];
        unsigned id[4];
        #pragma unroll
        for (int k = 0; k < 4; ++k) {
            id[k] = i0 + ((unsigned)k << 9) + (unsigned)tid;
            if (id[k] < cnt2) e[k] = bucket[e0 + id[k]];
        }
        #pragma unroll
        for (int k = 0; k < 4; ++k) {
            if (id[k] < cnt2)
                atomicAdd(&tile[e[k] & 4095u], entry_val(e[k]));
        }
    }
    __syncthreads();
    float* dst = partials + (((size_t)m * T + t) << 12);
    for (int i = tid; i < 4096; i += 512) dst[i] = tile[i];
}

// K5b: accum_img — fallback (NB<16 groups): one block per tile, write img.
__global__ __launch_bounds__(1024) void accum_img_kernel(
        const unsigned* __restrict__ bucket, const unsigned* __restrict__ tileBase,
        const unsigned* __restrict__ total, float* __restrict__ img, int bstart) {
    __shared__ float tile[4096];
    int t = blockIdx.x;
    int tid = threadIdx.x;
    for (int i = tid; i < 4096; i += 1024) tile[i] = 0.f;
    __syncthreads();
    unsigned s0 = tileBase[t];
    unsigned cntt = total[t];
    for (unsigned i0 = 0; i0 < cntt; i0 += 4096) {
        unsigned e[4];
        unsigned id[4];
        #pragma unroll
        for (int k = 0; k < 4; ++k) {
            id[k] = i0 + ((unsigned)k << 10) + (unsigned)tid;
            if (id[k] < cntt) e[k] = bucket[s0 + id[k]];
        }
        #pragma unroll
        for (int k = 0; k < 4; ++k) {
            if (id[k] < cntt)
                atomicAdd(&tile[e[k] & 4095u], entry_val(e[k]));
        }
    }
    __syncthreads();
    int b = bstart + (t >> 4);
    int band = t & 15;
    float4* dst = (float4*)(img + ((size_t)b << 16) + (band << 12));
    const float4* src = (const float4*)tile;
    for (int i = tid; i < 1024; i += 1024) dst[i] = src[i];
}

// ---------------------------------------------------------------------------
// Fallback: device-scope atomic scatter (R1 path) + zero
// ---------------------------------------------------------------------------
__global__ void zero_kernel(float4* __restrict__ p, int n4) {
    int i = blockIdx.x * blockDim.x + threadIdx.x;
    if (i < n4) p[i] = make_float4(0.f, 0.f, 0.f, 0.f);
}

__global__ __launch_bounds__(256) void scatter_atomic_kernel(
        const float* __restrict__ coords, const float* __restrict__ values,
        const float* __restrict__ Wd, const float* __restrict__ bd,
        const float* __restrict__ bdata, float* __restrict__ img) {
    __shared__ float P[BB * 16];
    P[threadIdx.x] = bdata[threadIdx.x];
    __syncthreads();
    int n = blockIdx.x * 256 + threadIdx.x;
    if (n >= NN) return;
    float cx = coords[n * 3 + 0];
    float cy = coords[n * 3 + 1];
    float cz = coords[n * 3 + 2];
    float base = values[n] + bd[n];
    float wd[LATD];
    #pragma unroll
    for (int l = 0; l < LATD; ++l) wd[l] = Wd[l * NN + n];
    #pragma unroll
    for (int b = 0; b < BB; ++b) {
        const float* Q = &P[b * 16];
        int2 p = project_px(Q, cx, cy, cz);
        float delta = 0.f;
        #pragma unroll
        for (int l = 0; l < LATD; ++l) delta = fmaf(Q[8 + l], wd[l], delta);
        atomicAdd(img + ((b << 16) | (p.y << 8) | p.x), base + delta);
    }
}

// ---------------------------------------------------------------------------
// Gaussian 7-tap weights (sigma=1, radius=3, normalized)
// ---------------------------------------------------------------------------
__device__ __constant__ float GW[4] = {0.39905027f, 0.24203623f, 0.05400558f, 0.00443305f};

// ---------------------------------------------------------------------------
// 256-point complex Stockham FFT in LDS, one 64-lane slice per FFT.
// ---------------------------------------------------------------------------
__device__ __forceinline__ void fft256(float2* src, float2* dst,
                                       const float2* __restrict__ TW,
                                       int lane, float dir) {
    #pragma unroll
    for (int t = 0; t < 8; ++t) {
        const int s = 1 << t;
        #pragma unroll
        for (int r = 0; r < 2; ++r) {
            int i = lane + (r << 6);
            int q = i & (s - 1);
            int p = i >> t;
            float2 a = src[q + s * p];
            float2 b = src[q + s * p + 128];
            int m = p << t;
            float cs = TW[m].x;
            float sn = dir * TW[m].y;
            float2 sum = make_float2(a.x + b.x, a.y + b.y);
            float dx = a.x - b.x;
            float dy = a.y - b.y;
            float2 tw = make_float2(dx * cs - dy * sn, dx * sn + dy * cs);
            int o = q + ((p * s) << 1);
            dst[o] = sum;
            dst[o + s] = tw;
        }
        __syncthreads();
        float2* tmp = src; src = dst; dst = tmp;
    }
}

__device__ __forceinline__ void fill_tw256(float2* TW, int tid) {
    if (tid < 128) {
        float sn, cs;
        sincosf(0.0245436926061703f * (float)tid, &sn, &cs);
        TW[tid] = make_float2(cs, sn);
    }
}

// ---------------------------------------------------------------------------
// K6: (sum M partials) + x-blur + forward row rFFT, 4 rows per block.
// M==0: read img directly (fallback paths).
// ---------------------------------------------------------------------------
__global__ __launch_bounds__(256) void fft_rows_fwd(const float* __restrict__ img,
                                                    const float* __restrict__ partials,
                                                    int M,
                                                    float2* __restrict__ Freq) {
    __shared__ float2 bufA[4][256];
    __shared__ float2 bufB[4][256];
    __shared__ float2 TW[128];
    __shared__ float  rowr[4][256];
    int tid = threadIdx.x;
    int lane = tid & 63;
    int sub = tid >> 6;
    fill_tw256(TW, tid);
    int b  = blockIdx.x >> 6;
    int y0 = (blockIdx.x & 63) << 2;

    if (M > 0) {
        // 4 consecutive rows live contiguously inside tile (b, y0>>4)
        int t = (b << 4) | (y0 >> 4);
        const float* pb = partials + ((size_t)t << 12) + ((y0 & 15) << 8);
        const size_t mstr = (size_t)256 << 12;   // stride between partial sets
        for (int i = tid; i < 1024; i += 256) {
            float s = 0.f;
            for (int m = 0; m < M; ++m) s += pb[(size_t)m * mstr + i];
            ((float*)rowr)[i] = s;
        }
    } else {
        const float* src = img + (((size_t)(b << 8) + y0) << 8);
        for (int i = tid; i < 1024; i += 256) ((float*)rowr)[i] = src[i];
    }
    __syncthreads();

    #pragma unroll
    for (int j = 0; j < 4; ++j) {
        int x = lane + (j << 6);
        float acc = GW[0] * rowr[sub][x];
        #pragma unroll
        for (int t = 1; t <= 3; ++t) {
            if (x - t >= 0)  acc += GW[t] * rowr[sub][x - t];
            if (x + t < 256) acc += GW[t] * rowr[sub][x + t];
        }
        bufA[sub][x] = make_float2(acc, 0.f);
    }
    __syncthreads();
    fft256(bufA[sub], bufB[sub], TW, lane, -1.f);

    for (int i = tid; i < FREQ_COLS * 4; i += 256) {
        int col = i >> 2;
        int s   = i & 3;
        Freq[((size_t)(b * FREQ_COLS + col) << 8) + y0 + s] = bufA[s][col];
    }
}

// ---------------------------------------------------------------------------
// K7: column pass — y-blur (complex) + FFT + CTF + inverse FFT, 4 cols/block.
// ---------------------------------------------------------------------------
__global__ __launch_bounds__(256) void fft_cols_ctf(float2* __restrict__ Freq,
                                                    const float* __restrict__ ctf) {
    __shared__ float2 bufA[4][256];
    __shared__ float2 bufB[4][256];
    __shared__ float2 TW[128];
    int tid = threadIdx.x;
    int lane = tid & 63;
    int sub = tid >> 6;
    fill_tw256(TW, tid);
    int b  = blockIdx.x / 33;
    int c0 = (blockIdx.x - b * 33) << 2;
    int col  = c0 + sub;
    int colc = col < FREQ_COLS ? col : (FREQ_COLS - 1);
    float2* basep = Freq + ((size_t)(b * FREQ_COLS + colc) << 8);

    #pragma unroll
    for (int j = 0; j < 4; ++j) {
        int k = lane + (j << 6);
        bufB[sub][k] = basep[k];
    }
    __syncthreads();
    #pragma unroll
    for (int j = 0; j < 4; ++j) {
        int k = lane + (j << 6);
        float ax = GW[0] * bufB[sub][k].x;
        float ay = GW[0] * bufB[sub][k].y;
        #pragma unroll
        for (int t = 1; t <= 3; ++t) {
            if (k - t >= 0)  { ax += GW[t] * bufB[sub][k - t].x; ay += GW[t] * bufB[sub][k - t].y; }
            if (k + t < 256) { ax += GW[t] * bufB[sub][k + t].x; ay += GW[t] * bufB[sub][k + t].y; }
        }
        bufA[sub][k] = make_float2(ax, ay);
    }
    __syncthreads();
    fft256(bufA[sub], bufB[sub], TW, lane, -1.f);
    #pragma unroll
    for (int j = 0; j < 4; ++j) {
        int k = lane + (j << 6);
        float c = ctf[(size_t)((b << 8) | k) * FREQ_COLS + colc];
        bufA[sub][k].x *= c;
        bufA[sub][k].y *= c;
    }
    __syncthreads();
    fft256(bufA[sub], bufB[sub], TW, lane, +1.f);
    if (col < FREQ_COLS) {
        #pragma unroll
        for (int j = 0; j < 4; ++j) {
            int k = lane + (j << 6);
            basep[k] = bufA[sub][k];
        }
    }
}

// ---------------------------------------------------------------------------
// K8: Hermitian-extend + inverse row FFT + scale, 4 rows per block.
// ---------------------------------------------------------------------------
__global__ __launch_bounds__(256) void fft_rows_inv(const float2* __restrict__ Freq,
                                                    float* __restrict__ out) {
    __shared__ float2 bufA[4][256];
    __shared__ float2 bufB[4][256];
    __shared__ float2 TW[128];
    int tid = threadIdx.x;
    int lane = tid & 63;
    int sub = tid >> 6;
    fill_tw256(TW, tid);
    int b  = blockIdx.x >> 6;
    int y0 = (blockIdx.x & 63) << 2;

    for (int i = tid; i < FREQ_COLS * 4; i += 256) {
        int col = i >> 2;
        int s   = i & 3;
        bufA[s][col] = Freq[((size_t)(b * FREQ_COLS + col) << 8) + y0 + s];
    }
    __syncthreads();
    for (int k = FREQ_COLS + lane; k < 256; k += 64) {
        float2 v = bufA[sub][256 - k];
        bufA[sub][k] = make_float2(v.x, -v.y);
    }
    __syncthreads();
    fft256(bufA[sub], bufB[sub], TW, lane, +1.f);
    float* dst = out + (((size_t)(b << 8) + y0) << 8);
    const float scale = 1.0f / 65536.0f;
    for (int i = tid; i < 1024; i += 256) {
        dst[i] = bufA[i >> 8][i & 255].x * scale;
    }
}

// ---------------------------------------------------------------------------
template<int NB>
static void run_binned(const float* coords, const float* values, const float* Wd,
                       const float* bd, float* bdata, unsigned* cnt, unsigned* bases,
                       unsigned* total, unsigned* tileBase, unsigned* bucket,
                       float* img, float* partials, int M, hipStream_t stream) {
    constexpr int T = NB * 16;
    const int NG = BB / NB;
    for (int g = 0; g < NG; ++g) {
        int bstart = g * NB;
        count_kernel<NB><<<NBLK, 256, 0, stream>>>(coords, bdata, cnt, bstart);
        scan_cols_kernel<<<T, 256, 0, stream>>>(cnt, bases, total, T);
        scan_small_kernel<<<1, 256, 0, stream>>>(total, tileBase, T);
        fill_kernel<NB><<<NBLK, 256, 0, stream>>>(coords, values, Wd, bd, bdata,
                                                  bases, tileBase, bucket, bstart);
        if (NB == 16 && M > 0) {
            accum_split_kernel<<<T * M, 512, 0, stream>>>(bucket, tileBase, total,
                                                          partials, T, M);
        } else {
            accum_img_kernel<<<T, 1024, 0, stream>>>(bucket, tileBase, total, img, bstart);
        }
    }
}

extern "C" void kernel_launch(void* const* d_in, const int* in_sizes, int n_in,
                              void* d_out, int out_size, void* d_ws, size_t ws_size,
                              hipStream_t stream) {
    const float* rows   = (const float*)d_in[0];
    const float* shifts = (const float*)d_in[1];
    const float* latent = (const float*)d_in[2];
    const float* coords = (const float*)d_in[3];
    const float* values = (const float*)d_in[4];
    const float* W0     = (const float*)d_in[5];
    const float* b0     = (const float*)d_in[6];
    const float* W1     = (const float*)d_in[7];
    const float* b1     = (const float*)d_in[8];
    const float* W2     = (const float*)d_in[9];
    const float* b2     = (const float*)d_in[10];
    const float* W3     = (const float*)d_in[11];
    const float* b3     = (const float*)d_in[12];
    const float* Wd     = (const float*)d_in[13];
    const float* bd     = (const float*)d_in[14];
    const float* ctf    = (const float*)d_in[15];
    float* out = (float*)d_out;

    // Workspace layout
    char* w = (char*)d_ws;
    size_t off = 0;
    float* bdata = (float*)(w + off);  off += 4096;
    float* img   = (float*)(w + off);  off += (size_t)IMG_ELEMS * 4;
    float2* Freq = (float2*)(w + off); off += (size_t)BB * FREQ_COLS * 256 * 8;
    unsigned* cnt   = (unsigned*)(w + off); off += (size_t)NBLK * 256 * 4;
    unsigned* bases = (unsigned*)(w + off); off += (size_t)NBLK * 256 * 4;
    unsigned* total = (unsigned*)(w + off); off += 1024;
    unsigned* tileBase = (unsigned*)(w + off); off += 1024;
    unsigned* bucket = (unsigned*)(w + off);
    size_t fixed = off;

    // NB=16 bucket: NN*16*4 = 32 MB; partials: M * 256 tiles * 16 KB = M*4 MB
    const size_t bucket16 = (size_t)NN * 16 * 4;
    float* partials = (float*)(w + fixed + bucket16);

    int NB = 0, M = 0;
    if      (ws_size >= fixed + bucket16 + 8ull * 4194304) { NB = 16; M = 8; }
    else if (ws_size >= fixed + bucket16 + 4ull * 4194304) { NB = 16; M = 4; }
    else if (ws_size >= fixed + bucket16 + 2ull * 4194304) { NB = 16; M = 2; }
    else if (ws_size >= fixed + bucket16)                   { NB = 16; M = 0; }
    else if (ws_size >= fixed + (size_t)NN *  8 * 4) NB = 8;
    else if (ws_size >= fixed + (size_t)NN *  4 * 4) NB = 4;
    else if (ws_size >= fixed + (size_t)NN *  2 * 4) NB = 2;
    else if (ws_size >= fixed + (size_t)NN *  1 * 4) NB = 1;

    prep_kernel<<<1, 64, 0, stream>>>(rows, shifts, latent,
                                      W0, b0, W1, b1, W2, b2, W3, b3, bdata);

    switch (NB) {
    case 16: run_binned<16>(coords, values, Wd, bd, bdata, cnt, bases, total, tileBase, bucket, img, partials, M, stream); break;
    case 8:  run_binned<8> (coords, values, Wd, bd, bdata, cnt, bases, total, tileBase, bucket, img, partials, 0, stream); break;
    case 4:  run_binned<4> (coords, values, Wd, bd, bdata, cnt, bases, total, tileBase, bucket, img, partials, 0, stream); break;
    case 2:  run_binned<2> (coords, values, Wd, bd, bdata, cnt, bases, total, tileBase, bucket, img, partials, 0, stream); break;
    case 1:  run_binned<1> (coords, values, Wd, bd, bdata, cnt, bases, total, tileBase, bucket, img, partials, 0, stream); break;
    default: {
        int n4 = IMG_ELEMS / 4;
        zero_kernel<<<(n4 + 255) / 256, 256, 0, stream>>>((float4*)img, n4);
        scatter_atomic_kernel<<<NBLK, 256, 0, stream>>>(coords, values, Wd, bd, bdata, img);
        M = 0;
    } break;
    }

    fft_rows_fwd<<<BB * 64, 256, 0, stream>>>(img, partials, (NB == 16) ? M : 0, Freq);
    fft_cols_ctf<<<BB * 33, 256, 0, stream>>>(Freq, ctf);
    fft_rows_inv<<<BB * 64, 256, 0, stream>>>(Freq, out);
}